// Round 2
// baseline (1966.337 us; speedup 1.0000x reference)
//
#include <hip/hip_runtime.h>
#include <math.h>

#define TOK   8192
#define DIM   256
#define NH    8
#define HDIM  32
#define FFD   1024
#define NE    8
#define NL    2
#define NOUT  1000
#define NSLOT 16384   // TOK*2

// ---------------- workspace layout (float units) ----------------
#define WS_X     ((size_t)0)
#define WS_LN    (WS_X    + (size_t)TOK*DIM)       // 2,097,152
#define WS_QKV   (WS_LN   + (size_t)TOK*DIM)       // 4,194,304
#define WS_H     (WS_QKV  + (size_t)TOK*3*DIM)     // 10,485,760  (NSLOT x 256 chunk)
#define WS_SOUT  (WS_H    + (size_t)NSLOT*256)     // 14,680,064  (NSLOT x 256)
#define WS_GV    (WS_SOUT + (size_t)NSLOT*256)     // 18,874,368  (TOK*2 gate weights)
#define WS_PP    (WS_GV   + (size_t)TOK*2)         // pool partials 8*32*256
#define WS_POOL  (WS_PP   + (size_t)8*32*256)
#define WS_INT   (WS_POOL + (size_t)8*256)         // int region from here

// int region layout (int32 indices)
#define IB_COUNTS   0     // [8]
#define IB_NTILES   8     // [1]
#define IB_OFFS     16    // [8]
#define IB_CURS     24    // [8]
#define IB_TILE_E   32    // [288]
#define IB_TILE_R0  320   // [288]
#define IB_TILE_RE  608   // [288]
#define IB_GIDX     896   // [TOK*2]
#define IB_SPOS     17280 // [TOK*2]
#define IB_STOK     33664 // [NSLOT]

__device__ __forceinline__ float gelu_exact(float v) {
    return 0.5f * v * (1.0f + erff(v * 0.70710678118654752f));
}

// ---------------- LayerNorm: one wave per token ----------------
__global__ __launch_bounds__(256) void ln_kernel(const float* __restrict__ x,
                                                 float* __restrict__ out,
                                                 const float* __restrict__ g,
                                                 const float* __restrict__ b) {
    int wave = threadIdx.x >> 6;
    int lane = threadIdx.x & 63;
    int t = blockIdx.x * 4 + wave;
    const float* xp = x + (size_t)t * DIM;
    float4 v = *(const float4*)&xp[lane * 4];
    float s = v.x + v.y + v.z + v.w;
    #pragma unroll
    for (int off = 32; off; off >>= 1) s += __shfl_xor(s, off);
    float mean = s * (1.0f / 256.0f);
    float dx = v.x - mean, dy = v.y - mean, dz = v.z - mean, dw = v.w - mean;
    float vs = dx * dx + dy * dy + dz * dz + dw * dw;
    #pragma unroll
    for (int off = 32; off; off >>= 1) vs += __shfl_xor(vs, off);
    float inv = rsqrtf(vs * (1.0f / 256.0f) + 1e-5f);
    float4 gg = *(const float4*)&g[lane * 4];
    float4 bb = *(const float4*)&b[lane * 4];
    float4 o;
    o.x = dx * inv * gg.x + bb.x;
    o.y = dy * inv * gg.y + bb.y;
    o.z = dz * inv * gg.z + bb.z;
    o.w = dw * inv * gg.w + bb.w;
    *(float4*)&out[(size_t)t * DIM + lane * 4] = o;
}

// ---------------- dense GEMM: C[M,N] = A[M,256] @ W[256,N] + bias (+residual) ----------------
template <bool RESIDUAL>
__global__ __launch_bounds__(256) void gemm_bias(const float* __restrict__ A,
                                                 const float* __restrict__ W,
                                                 const float* __restrict__ bias,
                                                 float* __restrict__ C, int N) {
    __shared__ float As[64][36];
    __shared__ float Ws[32][68];
    int tid = threadIdx.x;
    int tx = tid & 15, ty = tid >> 4;
    int row0 = blockIdx.x * 64, col0 = blockIdx.y * 64;
    float acc[4][4] = {};
    for (int k0 = 0; k0 < 256; k0 += 32) {
        #pragma unroll
        for (int l = 0; l < 2; ++l) {
            int lin = tid + l * 256;          // float4 index among 512
            int r = lin >> 3, c = (lin & 7) << 2;
            float4 v = *(const float4*)&A[(size_t)(row0 + r) * 256 + k0 + c];
            *(float4*)&As[r][c] = v;
        }
        #pragma unroll
        for (int l = 0; l < 2; ++l) {
            int lin = tid + l * 256;
            int r = lin >> 4, c = (lin & 15) << 2;
            float4 v = *(const float4*)&W[(size_t)(k0 + r) * N + col0 + c];
            *(float4*)&Ws[r][c] = v;
        }
        __syncthreads();
        #pragma unroll
        for (int kk = 0; kk < 32; ++kk) {
            float a[4], bfr[4];
            #pragma unroll
            for (int i = 0; i < 4; ++i) a[i] = As[ty * 4 + i][kk];
            #pragma unroll
            for (int j = 0; j < 4; ++j) bfr[j] = Ws[kk][tx * 4 + j];
            #pragma unroll
            for (int i = 0; i < 4; ++i)
                #pragma unroll
                for (int j = 0; j < 4; ++j) acc[i][j] += a[i] * bfr[j];
        }
        __syncthreads();
    }
    #pragma unroll
    for (int i = 0; i < 4; ++i) {
        int r = row0 + ty * 4 + i;
        #pragma unroll
        for (int j = 0; j < 4; ++j) {
            int c = col0 + tx * 4 + j;
            float v = acc[i][j] + bias[c];
            if (RESIDUAL) v += C[(size_t)r * N + c];
            C[(size_t)r * N + c] = v;
        }
    }
}

// ---------------- attention v2: thread per q-row, 16-wide score sub-tiles ----------------
__global__ __launch_bounds__(256) void attention_kernel(const float* __restrict__ qkv,
                                                        float* __restrict__ obuf) {
    int b = blockIdx.z, hh = blockIdx.y, qt = blockIdx.x;
    int sq = qt * 256 + threadIdx.x;
    const float* base = qkv + (size_t)b * 1024 * 768;
    const float scale = 0.17677669529663687f;
    float q[32];
    const float* qptr = base + (size_t)sq * 768 + hh * 32;
    #pragma unroll
    for (int i = 0; i < 8; ++i) {
        float4 v = *(const float4*)(qptr + i * 4);
        q[4 * i + 0] = v.x * scale;
        q[4 * i + 1] = v.y * scale;
        q[4 * i + 2] = v.z * scale;
        q[4 * i + 3] = v.w * scale;
    }
    float m = -1e30f, lsum = 0.0f;
    float o[32];
    #pragma unroll
    for (int i = 0; i < 32; ++i) o[i] = 0.0f;
    __shared__ float Kt[64][32];
    __shared__ float Vt[64][32];
    for (int kt = 0; kt < 16; ++kt) {
        __syncthreads();
        #pragma unroll
        for (int l = 0; l < 2; ++l) {
            int f4 = threadIdx.x + l * 256;   // 512 float4 per matrix
            int r = f4 >> 3, c = (f4 & 7) << 2;
            const float* kp = base + (size_t)(kt * 64 + r) * 768 + 256 + hh * 32 + c;
            *(float4*)&Kt[r][c] = *(const float4*)kp;
            const float* vp = base + (size_t)(kt * 64 + r) * 768 + 512 + hh * 32 + c;
            *(float4*)&Vt[r][c] = *(const float4*)vp;
        }
        __syncthreads();
        for (int jb = 0; jb < 4; ++jb) {
            // --- scores for 16 keys, all independent (ILP) ---
            float s[16];
            #pragma unroll
            for (int jj = 0; jj < 16; ++jj) {
                int j = jb * 16 + jj;
                float p0 = 0.f, p1 = 0.f, p2 = 0.f, p3 = 0.f;
                #pragma unroll
                for (int d4 = 0; d4 < 8; ++d4) {
                    float4 kk = *(const float4*)&Kt[j][d4 * 4];
                    p0 += q[4 * d4 + 0] * kk.x;
                    p1 += q[4 * d4 + 1] * kk.y;
                    p2 += q[4 * d4 + 2] * kk.z;
                    p3 += q[4 * d4 + 3] * kk.w;
                }
                s[jj] = (p0 + p1) + (p2 + p3);
            }
            // --- sub-tile max (tree) ---
            float t8[8];
            #pragma unroll
            for (int i = 0; i < 8; ++i) t8[i] = fmaxf(s[i], s[i + 8]);
            #pragma unroll
            for (int i = 0; i < 4; ++i) t8[i] = fmaxf(t8[i], t8[i + 4]);
            float mt = fmaxf(fmaxf(t8[0], t8[1]), fmaxf(t8[2], t8[3]));
            // --- single rescale per sub-tile ---
            float newm = fmaxf(m, mt);
            float corr = __expf(m - newm);
            m = newm;
            lsum *= corr;
            #pragma unroll
            for (int d = 0; d < 32; ++d) o[d] *= corr;
            // --- exp (independent) + sum tree ---
            #pragma unroll
            for (int jj = 0; jj < 16; ++jj) s[jj] = __expf(s[jj] - m);
            #pragma unroll
            for (int i = 0; i < 8; ++i) t8[i] = s[i] + s[i + 8];
            #pragma unroll
            for (int i = 0; i < 4; ++i) t8[i] = t8[i] + t8[i + 4];
            lsum += (t8[0] + t8[1]) + (t8[2] + t8[3]);
            // --- PV accumulate ---
            #pragma unroll
            for (int jj = 0; jj < 16; ++jj) {
                int j = jb * 16 + jj;
                float p = s[jj];
                #pragma unroll
                for (int d4 = 0; d4 < 8; ++d4) {
                    float4 vv = *(const float4*)&Vt[j][d4 * 4];
                    o[4 * d4 + 0] += p * vv.x;
                    o[4 * d4 + 1] += p * vv.y;
                    o[4 * d4 + 2] += p * vv.z;
                    o[4 * d4 + 3] += p * vv.w;
                }
            }
        }
    }
    float inv = 1.0f / lsum;
    float* op = obuf + (size_t)(b * 1024 + sq) * 256 + hh * 32;
    #pragma unroll
    for (int i = 0; i < 8; ++i) {
        float4 v;
        v.x = o[4 * i] * inv; v.y = o[4 * i + 1] * inv;
        v.z = o[4 * i + 2] * inv; v.w = o[4 * i + 3] * inv;
        *(float4*)(op + i * 4) = v;
    }
}

// ---------------- gate + top2 ----------------
__global__ __launch_bounds__(256) void gate_topk(const float* __restrict__ lnb,
                                                 const float* __restrict__ gw,
                                                 const float* __restrict__ gb,
                                                 float* __restrict__ gv, int* __restrict__ ib) {
    int t = blockIdx.x * blockDim.x + threadIdx.x;
    const float* x = lnb + (size_t)t * DIM;
    float g[8];
    #pragma unroll
    for (int e = 0; e < 8; ++e) g[e] = gb[e];
    for (int d4 = 0; d4 < 64; ++d4) {
        float4 xv = *(const float4*)&x[d4 * 4];
        const float* w0 = gw + (size_t)(d4 * 4) * 8;
        #pragma unroll
        for (int e = 0; e < 8; ++e) g[e] += xv.x * w0[e];
        #pragma unroll
        for (int e = 0; e < 8; ++e) g[e] += xv.y * w0[8 + e];
        #pragma unroll
        for (int e = 0; e < 8; ++e) g[e] += xv.z * w0[16 + e];
        #pragma unroll
        for (int e = 0; e < 8; ++e) g[e] += xv.w * w0[24 + e];
    }
    int i0 = 0; float s0 = g[0];
    #pragma unroll
    for (int e = 1; e < 8; ++e) if (g[e] > s0) { s0 = g[e]; i0 = e; }
    int i1 = -1; float s1 = -1e30f;
    #pragma unroll
    for (int e = 0; e < 8; ++e) if (e != i0 && g[e] > s1) { s1 = g[e]; i1 = e; }
    float e1 = __expf(s1 - s0);
    float w0v = 1.0f / (1.0f + e1);
    float w1v = e1 / (1.0f + e1);
    gv[2 * t] = w0v; gv[2 * t + 1] = w1v;
    ib[IB_GIDX + 2 * t] = i0; ib[IB_GIDX + 2 * t + 1] = i1;
    atomicAdd(&ib[IB_COUNTS + i0], 1);
    atomicAdd(&ib[IB_COUNTS + i1], 1);
}

// ---------------- scan + tile table (single thread) ----------------
__global__ void scan_tiles(int* ib) {
    if (threadIdx.x != 0 || blockIdx.x != 0) return;
    int off = 0, idx = 0;
    for (int e = 0; e < 8; ++e) {
        ib[IB_OFFS + e] = off;
        ib[IB_CURS + e] = off;
        int n = ib[IB_COUNTS + e];
        int nt = (n + 63) >> 6;
        for (int i = 0; i < nt; ++i) {
            ib[IB_TILE_E + idx] = e;
            ib[IB_TILE_R0 + idx] = off + i * 64;
            int re = off + ((i + 1) * 64 < n ? (i + 1) * 64 : n);
            ib[IB_TILE_RE + idx] = re;
            ++idx;
        }
        off += n;
    }
    ib[IB_NTILES] = idx;
}

// ---------------- scatter to slots ----------------
__global__ __launch_bounds__(256) void scatter_slots(int* ib) {
    int t = blockIdx.x * blockDim.x + threadIdx.x;
    #pragma unroll
    for (int k = 0; k < 2; ++k) {
        int e = ib[IB_GIDX + 2 * t + k];
        int pos = atomicAdd(&ib[IB_CURS + e], 1);
        ib[IB_STOK + pos] = t;
        ib[IB_SPOS + 2 * t + k] = pos;
    }
}

// ---------------- grouped FFN1: h = gelu(X[slots] @ W1[:, c0:c0+256] + b1) ----------------
__global__ __launch_bounds__(256) void ffn1_kernel(const float* __restrict__ lnb,
                                                   const float* __restrict__ w1l,
                                                   const float* __restrict__ b1l,
                                                   float* __restrict__ h,
                                                   const int* __restrict__ ib, int c0) {
    int tileIdx = blockIdx.x;
    if (tileIdx >= ib[IB_NTILES]) return;
    int e = ib[IB_TILE_E + tileIdx];
    int row0 = ib[IB_TILE_R0 + tileIdx];
    int rowend = ib[IB_TILE_RE + tileIdx];
    __shared__ float As[64][36];
    __shared__ float Ws[32][68];
    __shared__ int tok[64];
    int tid = threadIdx.x;
    if (tid < 64) {
        int sr = row0 + tid;
        tok[tid] = (sr < rowend) ? ib[IB_STOK + sr] : ib[IB_STOK + row0];
    }
    __syncthreads();
    const float* W1 = w1l + (size_t)e * DIM * FFD;
    int tx = tid & 15, ty = tid >> 4;
    int coln0 = blockIdx.y * 64;
    float acc[4][4] = {};
    for (int k0 = 0; k0 < 256; k0 += 32) {
        #pragma unroll
        for (int l = 0; l < 2; ++l) {
            int lin = tid + l * 256;
            int r = lin >> 3, c = (lin & 7) << 2;
            float4 v = *(const float4*)&lnb[(size_t)tok[r] * 256 + k0 + c];
            *(float4*)&As[r][c] = v;
        }
        #pragma unroll
        for (int l = 0; l < 2; ++l) {
            int lin = tid + l * 256;
            int r = lin >> 4, c = (lin & 15) << 2;
            float4 v = *(const float4*)&W1[(size_t)(k0 + r) * FFD + c0 + coln0 + c];
            *(float4*)&Ws[r][c] = v;
        }
        __syncthreads();
        #pragma unroll
        for (int kk = 0; kk < 32; ++kk) {
            float a[4], bfr[4];
            #pragma unroll
            for (int i = 0; i < 4; ++i) a[i] = As[ty * 4 + i][kk];
            #pragma unroll
            for (int j = 0; j < 4; ++j) bfr[j] = Ws[kk][tx * 4 + j];
            #pragma unroll
            for (int i = 0; i < 4; ++i)
                #pragma unroll
                for (int j = 0; j < 4; ++j) acc[i][j] += a[i] * bfr[j];
        }
        __syncthreads();
    }
    #pragma unroll
    for (int i = 0; i < 4; ++i) {
        int sr = row0 + ty * 4 + i;
        if (sr < rowend) {
            #pragma unroll
            for (int j = 0; j < 4; ++j) {
                int cl = coln0 + tx * 4 + j;          // chunk-local col
                float v = acc[i][j] + b1l[(size_t)e * FFD + c0 + cl];
                h[(size_t)sr * 256 + cl] = gelu_exact(v);
            }
        }
    }
}

// ---------------- grouped FFN2: slotout (+)= h @ W2[c0:c0+256, :] (+ b2 on first chunk) ----------------
__global__ __launch_bounds__(256) void ffn2_kernel(const float* __restrict__ h,
                                                   const float* __restrict__ w2l,
                                                   const float* __restrict__ b2l,
                                                   float* __restrict__ sout,
                                                   const int* __restrict__ ib, int c0) {
    int tileIdx = blockIdx.x;
    if (tileIdx >= ib[IB_NTILES]) return;
    int e = ib[IB_TILE_E + tileIdx];
    int row0 = ib[IB_TILE_R0 + tileIdx];
    int rowend = ib[IB_TILE_RE + tileIdx];
    __shared__ float As[64][36];
    __shared__ float Ws[32][68];
    const float* W2 = w2l + (size_t)e * FFD * DIM;
    int tid = threadIdx.x;
    int tx = tid & 15, ty = tid >> 4;
    int coln0 = blockIdx.y * 64;
    float acc[4][4] = {};
    for (int k0 = 0; k0 < 256; k0 += 32) {
        #pragma unroll
        for (int l = 0; l < 2; ++l) {
            int lin = tid + l * 256;
            int r = lin >> 3, c = (lin & 7) << 2;
            float4 v = *(const float4*)&h[(size_t)(row0 + r) * 256 + k0 + c];
            *(float4*)&As[r][c] = v;
        }
        #pragma unroll
        for (int l = 0; l < 2; ++l) {
            int lin = tid + l * 256;
            int r = lin >> 4, c = (lin & 15) << 2;
            float4 v = *(const float4*)&W2[(size_t)(c0 + k0 + r) * DIM + coln0 + c];
            *(float4*)&Ws[r][c] = v;
        }
        __syncthreads();
        #pragma unroll
        for (int kk = 0; kk < 32; ++kk) {
            float a[4], bfr[4];
            #pragma unroll
            for (int i = 0; i < 4; ++i) a[i] = As[ty * 4 + i][kk];
            #pragma unroll
            for (int j = 0; j < 4; ++j) bfr[j] = Ws[kk][tx * 4 + j];
            #pragma unroll
            for (int i = 0; i < 4; ++i)
                #pragma unroll
                for (int j = 0; j < 4; ++j) acc[i][j] += a[i] * bfr[j];
        }
        __syncthreads();
    }
    #pragma unroll
    for (int i = 0; i < 4; ++i) {
        int sr = row0 + ty * 4 + i;
        if (sr < rowend) {
            #pragma unroll
            for (int j = 0; j < 4; ++j) {
                int n = coln0 + tx * 4 + j;
                size_t oidx = (size_t)sr * 256 + n;
                if (c0 == 0) sout[oidx] = acc[i][j] + b2l[(size_t)e * DIM + n];
                else         sout[oidx] += acc[i][j];
            }
        }
    }
}

// ---------------- gather: x += g0*sout[p0] + g1*sout[p1] ----------------
__global__ __launch_bounds__(64) void moe_gather(float* __restrict__ xb,
                                                 const float* __restrict__ sout,
                                                 const float* __restrict__ gv,
                                                 const int* __restrict__ ib) {
    int t = blockIdx.x;
    int d = threadIdx.x * 4;
    int p0 = ib[IB_SPOS + 2 * t], p1 = ib[IB_SPOS + 2 * t + 1];
    float g0 = gv[2 * t], g1 = gv[2 * t + 1];
    float4 xv = *(float4*)&xb[(size_t)t * 256 + d];
    float4 s0 = *(const float4*)&sout[(size_t)p0 * 256 + d];
    float4 s1 = *(const float4*)&sout[(size_t)p1 * 256 + d];
    xv.x += g0 * s0.x + g1 * s1.x;
    xv.y += g0 * s0.y + g1 * s1.y;
    xv.z += g0 * s0.z + g1 * s1.z;
    xv.w += g0 * s0.w + g1 * s1.w;
    *(float4*)&xb[(size_t)t * 256 + d] = xv;
}

// ---------------- pooling ----------------
__global__ __launch_bounds__(256) void pool1(const float* __restrict__ xb, float* __restrict__ pp) {
    int b = blockIdx.x, ch = blockIdx.y, d = threadIdx.x;
    float s = 0.0f;
    for (int i = 0; i < 32; ++i) s += xb[((size_t)b * 1024 + ch * 32 + i) * 256 + d];
    pp[(size_t)(b * 32 + ch) * 256 + d] = s;
}
__global__ __launch_bounds__(256) void pool2(const float* __restrict__ pp, float* __restrict__ pool) {
    int b = blockIdx.x, d = threadIdx.x;
    float s = 0.0f;
    for (int c = 0; c < 32; ++c) s += pp[(size_t)(b * 32 + c) * 256 + d];
    pool[(size_t)b * 256 + d] = s * (1.0f / 1024.0f);
}

// ---------------- head ----------------
__global__ __launch_bounds__(256) void head_kernel(const float* __restrict__ pool,
                                                   const float* __restrict__ hw,
                                                   const float* __restrict__ hb,
                                                   float* __restrict__ out) {
    __shared__ float P[2048];
    int tid = threadIdx.x;
    for (int i = tid; i < 2048; i += 256) P[i] = pool[i];
    __syncthreads();
    int j = blockIdx.x * 256 + tid;
    if (j >= NOUT) return;
    float acc[8] = {};
    for (int d = 0; d < 256; ++d) {
        float w = hw[(size_t)d * NOUT + j];
        #pragma unroll
        for (int b = 0; b < 8; ++b) acc[b] += P[b * 256 + d] * w;
    }
    #pragma unroll
    for (int b = 0; b < 8; ++b) out[(size_t)b * NOUT + j] = acc[b] + hb[j];
}

extern "C" void kernel_launch(void* const* d_in, const int* in_sizes, int n_in,
                              void* d_out, int out_size, void* d_ws, size_t ws_size,
                              hipStream_t stream) {
    const float* x      = (const float*)d_in[0];
    const float* qkv_w  = (const float*)d_in[1];
    const float* qkv_b  = (const float*)d_in[2];
    const float* attn_w = (const float*)d_in[3];
    const float* attn_b = (const float*)d_in[4];
    const float* gate_w = (const float*)d_in[5];
    const float* gate_b = (const float*)d_in[6];
    const float* e_w1   = (const float*)d_in[7];
    const float* e_b1   = (const float*)d_in[8];
    const float* e_w2   = (const float*)d_in[9];
    const float* e_b2   = (const float*)d_in[10];
    const float* ln1_g  = (const float*)d_in[11];
    const float* ln1_b  = (const float*)d_in[12];
    const float* ln2_g  = (const float*)d_in[13];
    const float* ln2_b  = (const float*)d_in[14];
    const float* head_w = (const float*)d_in[15];
    const float* head_b = (const float*)d_in[16];
    float* out = (float*)d_out;
    float* wsf = (float*)d_ws;

    float* xb   = wsf + WS_X;
    float* lnb  = wsf + WS_LN;
    float* qkvb = wsf + WS_QKV;
    float* hb   = wsf + WS_H;
    float* sob  = wsf + WS_SOUT;
    float* gv   = wsf + WS_GV;
    float* pp   = wsf + WS_PP;
    float* pool = wsf + WS_POOL;
    int*   ib   = (int*)(wsf + WS_INT);

    hipMemcpyAsync(xb, x, (size_t)TOK * DIM * sizeof(float), hipMemcpyDeviceToDevice, stream);

    for (int l = 0; l < NL; ++l) {
        // --- attention block ---
        ln_kernel<<<TOK / 4, 256, 0, stream>>>(xb, lnb, ln1_g, ln1_b);
        gemm_bias<false><<<dim3(TOK / 64, 12), 256, 0, stream>>>(
            lnb, qkv_w + (size_t)l * DIM * 3 * DIM, qkv_b + (size_t)l * 3 * DIM, qkvb, 768);
        attention_kernel<<<dim3(4, NH, 8), 256, 0, stream>>>(qkvb, lnb);
        gemm_bias<true><<<dim3(TOK / 64, 4), 256, 0, stream>>>(
            lnb, attn_w + (size_t)l * DIM * DIM, attn_b + (size_t)l * DIM, xb, 256);

        // --- MoE block ---
        ln_kernel<<<TOK / 4, 256, 0, stream>>>(xb, lnb, ln2_g, ln2_b);
        hipMemsetAsync(ib, 0, 64, stream);
        gate_topk<<<TOK / 256, 256, 0, stream>>>(
            lnb, gate_w + (size_t)l * DIM * NE, gate_b + (size_t)l * NE, gv, ib);
        scan_tiles<<<1, 64, 0, stream>>>(ib);
        scatter_slots<<<TOK / 256, 256, 0, stream>>>(ib);
        for (int c = 0; c < 4; ++c) {
            ffn1_kernel<<<dim3(272, 4), 256, 0, stream>>>(
                lnb, e_w1 + (size_t)l * NE * DIM * FFD, e_b1 + (size_t)l * NE * FFD, hb, ib, c * 256);
            ffn2_kernel<<<dim3(272, 4), 256, 0, stream>>>(
                hb, e_w2 + (size_t)l * NE * FFD * DIM, e_b2 + (size_t)l * NE * DIM, sob, ib, c * 256);
        }
        moe_gather<<<TOK, 64, 0, stream>>>(xb, sob, gv, ib);
    }

    pool1<<<dim3(8, 32), 256, 0, stream>>>(xb, pp);
    pool2<<<8, 256, 0, stream>>>(pp, pool);
    head_kernel<<<4, 256, 0, stream>>>(pool, head_w, head_b, out);
}

// Round 3
// 1613.231 us; speedup vs baseline: 1.2189x; 1.2189x over previous
//
#include <hip/hip_runtime.h>
#include <math.h>

#define TOK   8192
#define DIM   256
#define NH    8
#define HDIM  32
#define FFD   1024
#define NE    8
#define NL    2
#define NOUT  1000
#define NSLOT 16384   // TOK*2
#define NSPLIT 4

// ---------------- workspace layout (float units) ----------------
#define WS_X     ((size_t)0)
#define WS_LN    (WS_X    + (size_t)TOK*DIM)
#define WS_QKV   (WS_LN   + (size_t)TOK*DIM)
#define WS_H     (WS_QKV  + (size_t)TOK*3*DIM)     // MoE h chunk; aliased as attention po
#define WS_SOUT  (WS_H    + (size_t)NSLOT*256)     // MoE slot-out; aliased as attention po (2nd half)
#define WS_GV    (WS_SOUT + (size_t)NSLOT*256)
#define WS_PP    (WS_GV   + (size_t)TOK*2)
#define WS_POOL  (WS_PP   + (size_t)8*32*256)
#define WS_INT   (WS_POOL + (size_t)8*256)         // int region from here (50,048 ints)
#define WS_PM    (WS_INT  + (size_t)50048)         // [B*NH*NSPLIT*1024] = 262144
#define WS_PL    (WS_PM   + (size_t)262144)        // [262144]

// attention po aliases WS_H..WS_GV : B*NH*NSPLIT*1024 rows x 32 = 8,388,608 floats exactly

// int region layout (int32 indices)
#define IB_COUNTS   0     // [8]
#define IB_NTILES   8     // [1]
#define IB_OFFS     16    // [8]
#define IB_CURS     24    // [8]
#define IB_TILE_E   32    // [288]
#define IB_TILE_R0  320   // [288]
#define IB_TILE_RE  608   // [288]
#define IB_GIDX     896   // [TOK*2]
#define IB_SPOS     17280 // [TOK*2]
#define IB_STOK     33664 // [NSLOT]

__device__ __forceinline__ float gelu_exact(float v) {
    return 0.5f * v * (1.0f + erff(v * 0.70710678118654752f));
}

// ---------------- LayerNorm: one wave per token ----------------
__global__ __launch_bounds__(256) void ln_kernel(const float* __restrict__ x,
                                                 float* __restrict__ out,
                                                 const float* __restrict__ g,
                                                 const float* __restrict__ b) {
    int wave = threadIdx.x >> 6;
    int lane = threadIdx.x & 63;
    int t = blockIdx.x * 4 + wave;
    const float* xp = x + (size_t)t * DIM;
    float4 v = *(const float4*)&xp[lane * 4];
    float s = v.x + v.y + v.z + v.w;
    #pragma unroll
    for (int off = 32; off; off >>= 1) s += __shfl_xor(s, off);
    float mean = s * (1.0f / 256.0f);
    float dx = v.x - mean, dy = v.y - mean, dz = v.z - mean, dw = v.w - mean;
    float vs = dx * dx + dy * dy + dz * dz + dw * dw;
    #pragma unroll
    for (int off = 32; off; off >>= 1) vs += __shfl_xor(vs, off);
    float inv = rsqrtf(vs * (1.0f / 256.0f) + 1e-5f);
    float4 gg = *(const float4*)&g[lane * 4];
    float4 bb = *(const float4*)&b[lane * 4];
    float4 o;
    o.x = dx * inv * gg.x + bb.x;
    o.y = dy * inv * gg.y + bb.y;
    o.z = dz * inv * gg.z + bb.z;
    o.w = dw * inv * gg.w + bb.w;
    *(float4*)&out[(size_t)t * DIM + lane * 4] = o;
}

// ---------------- dense GEMM: C[M,N] = A[M,256] @ W[256,N] + bias (+residual) ----------------
template <bool RESIDUAL>
__global__ __launch_bounds__(256) void gemm_bias(const float* __restrict__ A,
                                                 const float* __restrict__ W,
                                                 const float* __restrict__ bias,
                                                 float* __restrict__ C, int N) {
    __shared__ float As[64][36];
    __shared__ float Ws[32][68];
    int tid = threadIdx.x;
    int tx = tid & 15, ty = tid >> 4;
    int row0 = blockIdx.x * 64, col0 = blockIdx.y * 64;
    float acc[4][4] = {};
    for (int k0 = 0; k0 < 256; k0 += 32) {
        #pragma unroll
        for (int l = 0; l < 2; ++l) {
            int lin = tid + l * 256;          // float4 index among 512
            int r = lin >> 3, c = (lin & 7) << 2;
            float4 v = *(const float4*)&A[(size_t)(row0 + r) * 256 + k0 + c];
            *(float4*)&As[r][c] = v;
        }
        #pragma unroll
        for (int l = 0; l < 2; ++l) {
            int lin = tid + l * 256;
            int r = lin >> 4, c = (lin & 15) << 2;
            float4 v = *(const float4*)&W[(size_t)(k0 + r) * N + col0 + c];
            *(float4*)&Ws[r][c] = v;
        }
        __syncthreads();
        #pragma unroll
        for (int kk = 0; kk < 32; ++kk) {
            float a[4], bfr[4];
            #pragma unroll
            for (int i = 0; i < 4; ++i) a[i] = As[ty * 4 + i][kk];
            #pragma unroll
            for (int j = 0; j < 4; ++j) bfr[j] = Ws[kk][tx * 4 + j];
            #pragma unroll
            for (int i = 0; i < 4; ++i)
                #pragma unroll
                for (int j = 0; j < 4; ++j) acc[i][j] += a[i] * bfr[j];
        }
        __syncthreads();
    }
    #pragma unroll
    for (int i = 0; i < 4; ++i) {
        int r = row0 + ty * 4 + i;
        #pragma unroll
        for (int j = 0; j < 4; ++j) {
            int c = col0 + tx * 4 + j;
            float v = acc[i][j] + bias[c];
            if (RESIDUAL) v += C[(size_t)r * N + c];
            C[(size_t)r * N + c] = v;
        }
    }
}

// ---------------- attention v3: KV-split (flash-decode), thread per q-row ----------------
__global__ __launch_bounds__(256) void attention_split(const float* __restrict__ qkv,
                                                       float* __restrict__ po,
                                                       float* __restrict__ pm,
                                                       float* __restrict__ pl) {
    int b = blockIdx.z, hh = blockIdx.y;
    int qt = blockIdx.x >> 2, split = blockIdx.x & 3;
    int sq = qt * 256 + threadIdx.x;
    const float* base = qkv + (size_t)b * 1024 * 768;
    const float scale = 0.17677669529663687f;
    float q[32];
    const float* qptr = base + (size_t)sq * 768 + hh * 32;
    #pragma unroll
    for (int i = 0; i < 8; ++i) {
        float4 v = *(const float4*)(qptr + i * 4);
        q[4 * i + 0] = v.x * scale;
        q[4 * i + 1] = v.y * scale;
        q[4 * i + 2] = v.z * scale;
        q[4 * i + 3] = v.w * scale;
    }
    float m = -1e30f, lsum = 0.0f;
    float o[32];
    #pragma unroll
    for (int i = 0; i < 32; ++i) o[i] = 0.0f;
    __shared__ float Kt[64][32];
    __shared__ float Vt[64][32];
    for (int kt = split * 4; kt < split * 4 + 4; ++kt) {
        __syncthreads();
        #pragma unroll
        for (int l = 0; l < 2; ++l) {
            int f4 = threadIdx.x + l * 256;   // 512 float4 per matrix
            int r = f4 >> 3, c = (f4 & 7) << 2;
            const float* kp = base + (size_t)(kt * 64 + r) * 768 + 256 + hh * 32 + c;
            *(float4*)&Kt[r][c] = *(const float4*)kp;
            const float* vp = base + (size_t)(kt * 64 + r) * 768 + 512 + hh * 32 + c;
            *(float4*)&Vt[r][c] = *(const float4*)vp;
        }
        __syncthreads();
        for (int jb = 0; jb < 4; ++jb) {
            float s[16];
            #pragma unroll
            for (int jj = 0; jj < 16; ++jj) {
                int j = jb * 16 + jj;
                float p0 = 0.f, p1 = 0.f, p2 = 0.f, p3 = 0.f;
                #pragma unroll
                for (int d4 = 0; d4 < 8; ++d4) {
                    float4 kk = *(const float4*)&Kt[j][d4 * 4];
                    p0 += q[4 * d4 + 0] * kk.x;
                    p1 += q[4 * d4 + 1] * kk.y;
                    p2 += q[4 * d4 + 2] * kk.z;
                    p3 += q[4 * d4 + 3] * kk.w;
                }
                s[jj] = (p0 + p1) + (p2 + p3);
            }
            float t8[8];
            #pragma unroll
            for (int i = 0; i < 8; ++i) t8[i] = fmaxf(s[i], s[i + 8]);
            #pragma unroll
            for (int i = 0; i < 4; ++i) t8[i] = fmaxf(t8[i], t8[i + 4]);
            float mt = fmaxf(fmaxf(t8[0], t8[1]), fmaxf(t8[2], t8[3]));
            float newm = fmaxf(m, mt);
            float corr = __expf(m - newm);
            m = newm;
            lsum *= corr;
            #pragma unroll
            for (int d = 0; d < 32; ++d) o[d] *= corr;
            #pragma unroll
            for (int jj = 0; jj < 16; ++jj) s[jj] = __expf(s[jj] - m);
            #pragma unroll
            for (int i = 0; i < 8; ++i) t8[i] = s[i] + s[i + 8];
            #pragma unroll
            for (int i = 0; i < 4; ++i) t8[i] = t8[i] + t8[i + 4];
            lsum += (t8[0] + t8[1]) + (t8[2] + t8[3]);
            #pragma unroll
            for (int jj = 0; jj < 16; ++jj) {
                int j = jb * 16 + jj;
                float p = s[jj];
                #pragma unroll
                for (int d4 = 0; d4 < 8; ++d4) {
                    float4 vv = *(const float4*)&Vt[j][d4 * 4];
                    o[4 * d4 + 0] += p * vv.x;
                    o[4 * d4 + 1] += p * vv.y;
                    o[4 * d4 + 2] += p * vv.z;
                    o[4 * d4 + 3] += p * vv.w;
                }
            }
        }
    }
    // write unnormalized partials
    size_t row = ((size_t)(b * NH + hh) * NSPLIT + split) * 1024 + sq;
    pm[row] = m;
    pl[row] = lsum;
    float* op = po + row * 32;
    #pragma unroll
    for (int i = 0; i < 8; ++i) {
        float4 v;
        v.x = o[4 * i]; v.y = o[4 * i + 1]; v.z = o[4 * i + 2]; v.w = o[4 * i + 3];
        *(float4*)(op + i * 4) = v;
    }
}

// ---------------- attention combine: merge NSPLIT partials ----------------
__global__ __launch_bounds__(256) void attention_combine(const float* __restrict__ po,
                                                         const float* __restrict__ pm,
                                                         const float* __restrict__ pl,
                                                         float* __restrict__ obuf) {
    int gid = blockIdx.x * 256 + threadIdx.x;   // total B*NH*1024*8 = 524288
    int d4 = gid & 7;
    int r = gid >> 3;                            // (b*NH+h)*1024 + sq
    int bh = r >> 10, sq = r & 1023;
    size_t rowbase = (size_t)bh * NSPLIT * 1024 + sq;
    float m0 = pm[rowbase], m1 = pm[rowbase + 1024], m2 = pm[rowbase + 2048], m3 = pm[rowbase + 3072];
    float m = fmaxf(fmaxf(m0, m1), fmaxf(m2, m3));
    float w0 = __expf(m0 - m), w1 = __expf(m1 - m), w2 = __expf(m2 - m), w3 = __expf(m3 - m);
    float l = w0 * pl[rowbase] + w1 * pl[rowbase + 1024] + w2 * pl[rowbase + 2048] + w3 * pl[rowbase + 3072];
    float4 a0 = *(const float4*)&po[(rowbase) * 32 + d4 * 4];
    float4 a1 = *(const float4*)&po[(rowbase + 1024) * 32 + d4 * 4];
    float4 a2 = *(const float4*)&po[(rowbase + 2048) * 32 + d4 * 4];
    float4 a3 = *(const float4*)&po[(rowbase + 3072) * 32 + d4 * 4];
    float inv = 1.0f / l;
    float4 acc;
    acc.x = (w0 * a0.x + w1 * a1.x + w2 * a2.x + w3 * a3.x) * inv;
    acc.y = (w0 * a0.y + w1 * a1.y + w2 * a2.y + w3 * a3.y) * inv;
    acc.z = (w0 * a0.z + w1 * a1.z + w2 * a2.z + w3 * a3.z) * inv;
    acc.w = (w0 * a0.w + w1 * a1.w + w2 * a2.w + w3 * a3.w) * inv;
    int h = bh & 7, b = bh >> 3;
    *(float4*)&obuf[(size_t)(b * 1024 + sq) * 256 + h * 32 + d4 * 4] = acc;
}

// ---------------- gate + top2 ----------------
__global__ __launch_bounds__(256) void gate_topk(const float* __restrict__ lnb,
                                                 const float* __restrict__ gw,
                                                 const float* __restrict__ gb,
                                                 float* __restrict__ gv, int* __restrict__ ib) {
    int t = blockIdx.x * blockDim.x + threadIdx.x;
    const float* x = lnb + (size_t)t * DIM;
    float g[8];
    #pragma unroll
    for (int e = 0; e < 8; ++e) g[e] = gb[e];
    for (int d4 = 0; d4 < 64; ++d4) {
        float4 xv = *(const float4*)&x[d4 * 4];
        const float* w0 = gw + (size_t)(d4 * 4) * 8;
        #pragma unroll
        for (int e = 0; e < 8; ++e) g[e] += xv.x * w0[e];
        #pragma unroll
        for (int e = 0; e < 8; ++e) g[e] += xv.y * w0[8 + e];
        #pragma unroll
        for (int e = 0; e < 8; ++e) g[e] += xv.z * w0[16 + e];
        #pragma unroll
        for (int e = 0; e < 8; ++e) g[e] += xv.w * w0[24 + e];
    }
    int i0 = 0; float s0 = g[0];
    #pragma unroll
    for (int e = 1; e < 8; ++e) if (g[e] > s0) { s0 = g[e]; i0 = e; }
    int i1 = -1; float s1 = -1e30f;
    #pragma unroll
    for (int e = 0; e < 8; ++e) if (e != i0 && g[e] > s1) { s1 = g[e]; i1 = e; }
    float e1 = __expf(s1 - s0);
    float w0v = 1.0f / (1.0f + e1);
    float w1v = e1 / (1.0f + e1);
    gv[2 * t] = w0v; gv[2 * t + 1] = w1v;
    ib[IB_GIDX + 2 * t] = i0; ib[IB_GIDX + 2 * t + 1] = i1;
    atomicAdd(&ib[IB_COUNTS + i0], 1);
    atomicAdd(&ib[IB_COUNTS + i1], 1);
}

// ---------------- scan + tile table (single thread) ----------------
__global__ void scan_tiles(int* ib) {
    if (threadIdx.x != 0 || blockIdx.x != 0) return;
    int off = 0, idx = 0;
    for (int e = 0; e < 8; ++e) {
        ib[IB_OFFS + e] = off;
        ib[IB_CURS + e] = off;
        int n = ib[IB_COUNTS + e];
        int nt = (n + 63) >> 6;
        for (int i = 0; i < nt; ++i) {
            ib[IB_TILE_E + idx] = e;
            ib[IB_TILE_R0 + idx] = off + i * 64;
            int re = off + ((i + 1) * 64 < n ? (i + 1) * 64 : n);
            ib[IB_TILE_RE + idx] = re;
            ++idx;
        }
        off += n;
    }
    ib[IB_NTILES] = idx;
}

// ---------------- scatter to slots ----------------
__global__ __launch_bounds__(256) void scatter_slots(int* ib) {
    int t = blockIdx.x * blockDim.x + threadIdx.x;
    #pragma unroll
    for (int k = 0; k < 2; ++k) {
        int e = ib[IB_GIDX + 2 * t + k];
        int pos = atomicAdd(&ib[IB_CURS + e], 1);
        ib[IB_STOK + pos] = t;
        ib[IB_SPOS + 2 * t + k] = pos;
    }
}

// ---------------- grouped FFN1: h = gelu(X[slots] @ W1[:, c0:c0+256] + b1) ----------------
__global__ __launch_bounds__(256) void ffn1_kernel(const float* __restrict__ lnb,
                                                   const float* __restrict__ w1l,
                                                   const float* __restrict__ b1l,
                                                   float* __restrict__ h,
                                                   const int* __restrict__ ib, int c0) {
    int tileIdx = blockIdx.x;
    if (tileIdx >= ib[IB_NTILES]) return;
    int e = ib[IB_TILE_E + tileIdx];
    int row0 = ib[IB_TILE_R0 + tileIdx];
    int rowend = ib[IB_TILE_RE + tileIdx];
    __shared__ float As[64][36];
    __shared__ float Ws[32][68];
    __shared__ int tok[64];
    int tid = threadIdx.x;
    if (tid < 64) {
        int sr = row0 + tid;
        tok[tid] = (sr < rowend) ? ib[IB_STOK + sr] : ib[IB_STOK + row0];
    }
    __syncthreads();
    const float* W1 = w1l + (size_t)e * DIM * FFD;
    int tx = tid & 15, ty = tid >> 4;
    int coln0 = blockIdx.y * 64;
    float acc[4][4] = {};
    for (int k0 = 0; k0 < 256; k0 += 32) {
        #pragma unroll
        for (int l = 0; l < 2; ++l) {
            int lin = tid + l * 256;
            int r = lin >> 3, c = (lin & 7) << 2;
            float4 v = *(const float4*)&lnb[(size_t)tok[r] * 256 + k0 + c];
            *(float4*)&As[r][c] = v;
        }
        #pragma unroll
        for (int l = 0; l < 2; ++l) {
            int lin = tid + l * 256;
            int r = lin >> 4, c = (lin & 15) << 2;
            float4 v = *(const float4*)&W1[(size_t)(k0 + r) * FFD + c0 + coln0 + c];
            *(float4*)&Ws[r][c] = v;
        }
        __syncthreads();
        #pragma unroll
        for (int kk = 0; kk < 32; ++kk) {
            float a[4], bfr[4];
            #pragma unroll
            for (int i = 0; i < 4; ++i) a[i] = As[ty * 4 + i][kk];
            #pragma unroll
            for (int j = 0; j < 4; ++j) bfr[j] = Ws[kk][tx * 4 + j];
            #pragma unroll
            for (int i = 0; i < 4; ++i)
                #pragma unroll
                for (int j = 0; j < 4; ++j) acc[i][j] += a[i] * bfr[j];
        }
        __syncthreads();
    }
    #pragma unroll
    for (int i = 0; i < 4; ++i) {
        int sr = row0 + ty * 4 + i;
        if (sr < rowend) {
            #pragma unroll
            for (int j = 0; j < 4; ++j) {
                int cl = coln0 + tx * 4 + j;          // chunk-local col
                float v = acc[i][j] + b1l[(size_t)e * FFD + c0 + cl];
                h[(size_t)sr * 256 + cl] = gelu_exact(v);
            }
        }
    }
}

// ---------------- grouped FFN2: slotout (+)= h @ W2[c0:c0+256, :] (+ b2 on first chunk) ----------------
__global__ __launch_bounds__(256) void ffn2_kernel(const float* __restrict__ h,
                                                   const float* __restrict__ w2l,
                                                   const float* __restrict__ b2l,
                                                   float* __restrict__ sout,
                                                   const int* __restrict__ ib, int c0) {
    int tileIdx = blockIdx.x;
    if (tileIdx >= ib[IB_NTILES]) return;
    int e = ib[IB_TILE_E + tileIdx];
    int row0 = ib[IB_TILE_R0 + tileIdx];
    int rowend = ib[IB_TILE_RE + tileIdx];
    __shared__ float As[64][36];
    __shared__ float Ws[32][68];
    const float* W2 = w2l + (size_t)e * FFD * DIM;
    int tid = threadIdx.x;
    int tx = tid & 15, ty = tid >> 4;
    int coln0 = blockIdx.y * 64;
    float acc[4][4] = {};
    for (int k0 = 0; k0 < 256; k0 += 32) {
        #pragma unroll
        for (int l = 0; l < 2; ++l) {
            int lin = tid + l * 256;
            int r = lin >> 3, c = (lin & 7) << 2;
            float4 v = *(const float4*)&h[(size_t)(row0 + r) * 256 + k0 + c];
            *(float4*)&As[r][c] = v;
        }
        #pragma unroll
        for (int l = 0; l < 2; ++l) {
            int lin = tid + l * 256;
            int r = lin >> 4, c = (lin & 15) << 2;
            float4 v = *(const float4*)&W2[(size_t)(c0 + k0 + r) * DIM + coln0 + c];
            *(float4*)&Ws[r][c] = v;
        }
        __syncthreads();
        #pragma unroll
        for (int kk = 0; kk < 32; ++kk) {
            float a[4], bfr[4];
            #pragma unroll
            for (int i = 0; i < 4; ++i) a[i] = As[ty * 4 + i][kk];
            #pragma unroll
            for (int j = 0; j < 4; ++j) bfr[j] = Ws[kk][tx * 4 + j];
            #pragma unroll
            for (int i = 0; i < 4; ++i)
                #pragma unroll
                for (int j = 0; j < 4; ++j) acc[i][j] += a[i] * bfr[j];
        }
        __syncthreads();
    }
    #pragma unroll
    for (int i = 0; i < 4; ++i) {
        int sr = row0 + ty * 4 + i;
        if (sr < rowend) {
            #pragma unroll
            for (int j = 0; j < 4; ++j) {
                int n = coln0 + tx * 4 + j;
                size_t oidx = (size_t)sr * 256 + n;
                if (c0 == 0) sout[oidx] = acc[i][j] + b2l[(size_t)e * DIM + n];
                else         sout[oidx] += acc[i][j];
            }
        }
    }
}

// ---------------- gather: x += g0*sout[p0] + g1*sout[p1] ----------------
__global__ __launch_bounds__(64) void moe_gather(float* __restrict__ xb,
                                                 const float* __restrict__ sout,
                                                 const float* __restrict__ gv,
                                                 const int* __restrict__ ib) {
    int t = blockIdx.x;
    int d = threadIdx.x * 4;
    int p0 = ib[IB_SPOS + 2 * t], p1 = ib[IB_SPOS + 2 * t + 1];
    float g0 = gv[2 * t], g1 = gv[2 * t + 1];
    float4 xv = *(float4*)&xb[(size_t)t * 256 + d];
    float4 s0 = *(const float4*)&sout[(size_t)p0 * 256 + d];
    float4 s1 = *(const float4*)&sout[(size_t)p1 * 256 + d];
    xv.x += g0 * s0.x + g1 * s1.x;
    xv.y += g0 * s0.y + g1 * s1.y;
    xv.z += g0 * s0.z + g1 * s1.z;
    xv.w += g0 * s0.w + g1 * s1.w;
    *(float4*)&xb[(size_t)t * 256 + d] = xv;
}

// ---------------- pooling ----------------
__global__ __launch_bounds__(256) void pool1(const float* __restrict__ xb, float* __restrict__ pp) {
    int b = blockIdx.x, ch = blockIdx.y, d = threadIdx.x;
    float s = 0.0f;
    for (int i = 0; i < 32; ++i) s += xb[((size_t)b * 1024 + ch * 32 + i) * 256 + d];
    pp[(size_t)(b * 32 + ch) * 256 + d] = s;
}
__global__ __launch_bounds__(256) void pool2(const float* __restrict__ pp, float* __restrict__ pool) {
    int b = blockIdx.x, d = threadIdx.x;
    float s = 0.0f;
    for (int c = 0; c < 32; ++c) s += pp[(size_t)(b * 32 + c) * 256 + d];
    pool[(size_t)b * 256 + d] = s * (1.0f / 1024.0f);
}

// ---------------- head ----------------
__global__ __launch_bounds__(256) void head_kernel(const float* __restrict__ pool,
                                                   const float* __restrict__ hw,
                                                   const float* __restrict__ hb,
                                                   float* __restrict__ out) {
    __shared__ float P[2048];
    int tid = threadIdx.x;
    for (int i = tid; i < 2048; i += 256) P[i] = pool[i];
    __syncthreads();
    int j = blockIdx.x * 256 + tid;
    if (j >= NOUT) return;
    float acc[8] = {};
    for (int d = 0; d < 256; ++d) {
        float w = hw[(size_t)d * NOUT + j];
        #pragma unroll
        for (int b = 0; b < 8; ++b) acc[b] += P[b * 256 + d] * w;
    }
    #pragma unroll
    for (int b = 0; b < 8; ++b) out[(size_t)b * NOUT + j] = acc[b] + hb[j];
}

extern "C" void kernel_launch(void* const* d_in, const int* in_sizes, int n_in,
                              void* d_out, int out_size, void* d_ws, size_t ws_size,
                              hipStream_t stream) {
    const float* x      = (const float*)d_in[0];
    const float* qkv_w  = (const float*)d_in[1];
    const float* qkv_b  = (const float*)d_in[2];
    const float* attn_w = (const float*)d_in[3];
    const float* attn_b = (const float*)d_in[4];
    const float* gate_w = (const float*)d_in[5];
    const float* gate_b = (const float*)d_in[6];
    const float* e_w1   = (const float*)d_in[7];
    const float* e_b1   = (const float*)d_in[8];
    const float* e_w2   = (const float*)d_in[9];
    const float* e_b2   = (const float*)d_in[10];
    const float* ln1_g  = (const float*)d_in[11];
    const float* ln1_b  = (const float*)d_in[12];
    const float* ln2_g  = (const float*)d_in[13];
    const float* ln2_b  = (const float*)d_in[14];
    const float* head_w = (const float*)d_in[15];
    const float* head_b = (const float*)d_in[16];
    float* out = (float*)d_out;
    float* wsf = (float*)d_ws;

    float* xb   = wsf + WS_X;
    float* lnb  = wsf + WS_LN;
    float* qkvb = wsf + WS_QKV;
    float* hb   = wsf + WS_H;
    float* sob  = wsf + WS_SOUT;
    float* gv   = wsf + WS_GV;
    float* pp   = wsf + WS_PP;
    float* pool = wsf + WS_POOL;
    int*   ib   = (int*)(wsf + WS_INT);
    float* po   = wsf + WS_H;    // alias: attention partial O (8.39M floats)
    float* pm   = wsf + WS_PM;
    float* pl   = wsf + WS_PL;

    hipMemcpyAsync(xb, x, (size_t)TOK * DIM * sizeof(float), hipMemcpyDeviceToDevice, stream);

    for (int l = 0; l < NL; ++l) {
        // --- attention block ---
        ln_kernel<<<TOK / 4, 256, 0, stream>>>(xb, lnb, ln1_g, ln1_b);
        gemm_bias<false><<<dim3(TOK / 64, 12), 256, 0, stream>>>(
            lnb, qkv_w + (size_t)l * DIM * 3 * DIM, qkv_b + (size_t)l * 3 * DIM, qkvb, 768);
        attention_split<<<dim3(4 * NSPLIT, NH, 8), 256, 0, stream>>>(qkvb, po, pm, pl);
        attention_combine<<<2048, 256, 0, stream>>>(po, pm, pl, lnb);
        gemm_bias<true><<<dim3(TOK / 64, 4), 256, 0, stream>>>(
            lnb, attn_w + (size_t)l * DIM * DIM, attn_b + (size_t)l * DIM, xb, 256);

        // --- MoE block ---
        ln_kernel<<<TOK / 4, 256, 0, stream>>>(xb, lnb, ln2_g, ln2_b);
        hipMemsetAsync(ib, 0, 64, stream);
        gate_topk<<<TOK / 256, 256, 0, stream>>>(
            lnb, gate_w + (size_t)l * DIM * NE, gate_b + (size_t)l * NE, gv, ib);
        scan_tiles<<<1, 64, 0, stream>>>(ib);
        scatter_slots<<<TOK / 256, 256, 0, stream>>>(ib);
        for (int c = 0; c < 4; ++c) {
            ffn1_kernel<<<dim3(272, 4), 256, 0, stream>>>(
                lnb, e_w1 + (size_t)l * NE * DIM * FFD, e_b1 + (size_t)l * NE * FFD, hb, ib, c * 256);
            ffn2_kernel<<<dim3(272, 4), 256, 0, stream>>>(
                hb, e_w2 + (size_t)l * NE * FFD * DIM, e_b2 + (size_t)l * NE * DIM, sob, ib, c * 256);
        }
        moe_gather<<<TOK, 64, 0, stream>>>(xb, sob, gv, ib);
    }

    pool1<<<dim3(8, 32), 256, 0, stream>>>(xb, pp);
    pool2<<<8, 256, 0, stream>>>(pp, pool);
    head_kernel<<<4, 256, 0, stream>>>(pool, head_w, head_b, out);
}

// Round 4
// 1255.902 us; speedup vs baseline: 1.5657x; 1.2845x over previous
//
#include <hip/hip_runtime.h>
#include <math.h>

#define TOK   8192
#define DIM   256
#define NH    8
#define HDIM  32
#define FFD   1024
#define NE    8
#define NL    2
#define NOUT  1000
#define NSLOT 16384   // TOK*2
#define NSPLIT 4

typedef unsigned int uint;
typedef unsigned short ushort;
typedef __attribute__((ext_vector_type(8))) short short8;
typedef __attribute__((ext_vector_type(4))) float f32x4;

// ---------------- workspace layout (float units) ----------------
#define WS_X     ((size_t)0)
#define WS_LN    (WS_X    + (size_t)TOK*DIM)       // 2,097,152
#define WS_QKV   (WS_LN   + (size_t)TOK*DIM)       // 4,194,304  (f32 qkvb 8192x768; aliased by w1T/w2T splits in MoE phase)
#define WS_H     (WS_QKV  + (size_t)TOK*3*DIM)     // 10,485,760 (h_hi/h_lo bf16; aliased by attention po)
#define WS_SOUT  (WS_H    + (size_t)NSLOT*256)     // 14,680,064 (sout f32; aliased by attention po 2nd half)
#define WS_GV    (WS_SOUT + (size_t)NSLOT*256)     // 18,874,368
#define WS_PP    (WS_GV   + (size_t)TOK*2)
#define WS_POOL  (WS_PP   + (size_t)8*32*256)
#define WS_INT   (WS_POOL + (size_t)8*256)
#define WS_PM    (WS_INT  + (size_t)50048)
#define WS_PL    (WS_PM   + (size_t)262144)
#define WS_U16   (WS_PL   + (size_t)262144)        // ushort area: ln splits + small weight splits

// int region layout (int32 indices)
#define IB_COUNTS   0
#define IB_NTILES   8
#define IB_OFFS     16
#define IB_CURS     24
#define IB_TILE_E   32
#define IB_TILE_R0  320
#define IB_TILE_RE  608
#define IB_GIDX     896
#define IB_SPOS     17280
#define IB_STOK     33664

__device__ __forceinline__ float gelu_exact(float v) {
    return 0.5f * v * (1.0f + erff(v * 0.70710678118654752f));
}

__device__ __forceinline__ ushort f32_bf16(float x) {
    uint u = __float_as_uint(x);
    return (ushort)((u + 0x7FFFu + ((u >> 16) & 1u)) >> 16);
}
__device__ __forceinline__ void split2(float x, ushort& h, ushort& lo) {
    uint u = __float_as_uint(x);
    uint hh = (u + 0x7FFFu + ((u >> 16) & 1u)) >> 16;
    h = (ushort)hh;
    float hf = __uint_as_float(hh << 16);
    float l = x - hf;
    uint ul = __float_as_uint(l);
    lo = (ushort)((ul + 0x7FFFu + ((ul >> 16) & 1u)) >> 16);
}

// ---------------- LayerNorm + bf16 split output ----------------
template<bool WF32>
__global__ __launch_bounds__(256) void ln_split(const float* __restrict__ x,
                                                float* __restrict__ out,
                                                ushort* __restrict__ ohi,
                                                ushort* __restrict__ olo,
                                                const float* __restrict__ g,
                                                const float* __restrict__ b) {
    int wave = threadIdx.x >> 6;
    int lane = threadIdx.x & 63;
    int t = blockIdx.x * 4 + wave;
    const float* xp = x + (size_t)t * DIM;
    float4 v = *(const float4*)&xp[lane * 4];
    float s = v.x + v.y + v.z + v.w;
    #pragma unroll
    for (int off = 32; off; off >>= 1) s += __shfl_xor(s, off);
    float mean = s * (1.0f / 256.0f);
    float dx = v.x - mean, dy = v.y - mean, dz = v.z - mean, dw = v.w - mean;
    float vs = dx * dx + dy * dy + dz * dz + dw * dw;
    #pragma unroll
    for (int off = 32; off; off >>= 1) vs += __shfl_xor(vs, off);
    float inv = rsqrtf(vs * (1.0f / 256.0f) + 1e-5f);
    float4 gg = *(const float4*)&g[lane * 4];
    float4 bb = *(const float4*)&b[lane * 4];
    float o0 = dx * inv * gg.x + bb.x;
    float o1 = dy * inv * gg.y + bb.y;
    float o2 = dz * inv * gg.z + bb.z;
    float o3 = dw * inv * gg.w + bb.w;
    size_t idx = (size_t)t * DIM + lane * 4;
    if (WF32) {
        float4 o; o.x = o0; o.y = o1; o.z = o2; o.w = o3;
        *(float4*)&out[idx] = o;
    }
    ushort h0, h1, h2, h3, l0, l1, l2, l3;
    split2(o0, h0, l0); split2(o1, h1, l1); split2(o2, h2, l2); split2(o3, h3, l3);
    uint2 ph, pl;
    ph.x = (uint)h0 | ((uint)h1 << 16); ph.y = (uint)h2 | ((uint)h3 << 16);
    pl.x = (uint)l0 | ((uint)l1 << 16); pl.y = (uint)l2 | ((uint)l3 << 16);
    *(uint2*)&ohi[idx] = ph;
    *(uint2*)&olo[idx] = pl;
}

// ---------------- split+transpose weights: src[K][N] (z matrices) -> T hi/lo [N][K] ----------------
__global__ __launch_bounds__(256) void split_transpose(const float* __restrict__ src,
                                                       ushort* __restrict__ dhi,
                                                       ushort* __restrict__ dlo,
                                                       int K, int N) {
    int z = blockIdx.z;
    const float* s = src + (size_t)z * K * N;
    ushort* th = dhi + (size_t)z * K * N;
    ushort* tl = dlo + (size_t)z * K * N;
    __shared__ float tile[32][33];
    int k0 = blockIdx.x * 32, n0 = blockIdx.y * 32;
    int tx = threadIdx.x & 31, ty = threadIdx.x >> 5;
    #pragma unroll
    for (int i = 0; i < 4; ++i) {
        int k = k0 + ty + i * 8;
        tile[ty + i * 8][tx] = s[(size_t)k * N + n0 + tx];
    }
    __syncthreads();
    #pragma unroll
    for (int i = 0; i < 4; ++i) {
        int n = n0 + ty + i * 8;
        float v = tile[tx][ty + i * 8];
        ushort h, lo;
        split2(v, h, lo);
        th[(size_t)n * K + k0 + tx] = h;
        tl[(size_t)n * K + k0 + tx] = lo;
    }
}

// ---------------- MFMA dense GEMM: C[M,N] (+)= split(A)[M,256] @ splitT(B)[N,256]^T + bias ----------------
template<bool RES>
__global__ __launch_bounds__(256) void mfma_dense(const ushort* __restrict__ Ah,
                                                  const ushort* __restrict__ Al,
                                                  const ushort* __restrict__ Bh,
                                                  const ushort* __restrict__ Bl,
                                                  const float* __restrict__ bias,
                                                  float* __restrict__ C, int N) {
    __shared__ ushort LA[2][64][40];
    __shared__ ushort LB[2][64][40];
    int tid = threadIdx.x;
    int row0 = blockIdx.x * 64, col0 = blockIdx.y * 64;
    int w = tid >> 6, l = tid & 63;
    f32x4 acc[4] = {};
    int r = tid >> 2, c8 = (tid & 3) * 8;
    size_t arow = (size_t)(row0 + r) * 256;
    size_t brow = (size_t)(col0 + r) * 256;
    for (int k0 = 0; k0 < 256; k0 += 32) {
        *(uint4*)&LA[0][r][c8] = *(const uint4*)&Ah[arow + k0 + c8];
        *(uint4*)&LA[1][r][c8] = *(const uint4*)&Al[arow + k0 + c8];
        *(uint4*)&LB[0][r][c8] = *(const uint4*)&Bh[brow + k0 + c8];
        *(uint4*)&LB[1][r][c8] = *(const uint4*)&Bl[brow + k0 + c8];
        __syncthreads();
        int ar = (w << 4) + (l & 15), kg = (l >> 4) << 3;
        short8 ah = *(const short8*)&LA[0][ar][kg];
        short8 al = *(const short8*)&LA[1][ar][kg];
        #pragma unroll
        for (int f = 0; f < 4; ++f) {
            int br = (f << 4) + (l & 15);
            short8 bh = *(const short8*)&LB[0][br][kg];
            short8 bl = *(const short8*)&LB[1][br][kg];
            acc[f] = __builtin_amdgcn_mfma_f32_16x16x32_bf16(ah, bh, acc[f], 0, 0, 0);
            acc[f] = __builtin_amdgcn_mfma_f32_16x16x32_bf16(ah, bl, acc[f], 0, 0, 0);
            acc[f] = __builtin_amdgcn_mfma_f32_16x16x32_bf16(al, bh, acc[f], 0, 0, 0);
        }
        __syncthreads();
    }
    int orow = row0 + (w << 4) + ((l >> 4) << 2);
    int oc = col0 + (l & 15);
    #pragma unroll
    for (int f = 0; f < 4; ++f) {
        int gc = oc + f * 16;
        float bv = bias[gc];
        #pragma unroll
        for (int rr = 0; rr < 4; ++rr) {
            size_t idx = (size_t)(orow + rr) * N + gc;
            float v = acc[f][rr] + bv;
            if (RES) v += C[idx];
            C[idx] = v;
        }
    }
}

// ---------------- MFMA FFN1 (gathered rows, gelu, split output) ----------------
__global__ __launch_bounds__(256) void mfma_ffn1(const ushort* __restrict__ Ah,
                                                 const ushort* __restrict__ Al,
                                                 const ushort* __restrict__ W1h,
                                                 const ushort* __restrict__ W1l,
                                                 const float* __restrict__ b1l,
                                                 ushort* __restrict__ hh,
                                                 ushort* __restrict__ hl,
                                                 const int* __restrict__ ib, int c0) {
    int tileIdx = blockIdx.x;
    if (tileIdx >= ib[IB_NTILES]) return;
    int e = ib[IB_TILE_E + tileIdx];
    int row0 = ib[IB_TILE_R0 + tileIdx];
    int rowend = ib[IB_TILE_RE + tileIdx];
    __shared__ ushort LA[2][64][40];
    __shared__ ushort LB[2][64][40];
    __shared__ int tok[64];
    int tid = threadIdx.x;
    if (tid < 64) {
        int sr = row0 + tid;
        tok[tid] = ib[IB_STOK + (sr < rowend ? sr : row0)];
    }
    __syncthreads();
    int coln0 = blockIdx.y * 64;
    const ushort* Bh = W1h + (size_t)e * 262144 + (size_t)(c0 + coln0) * 256;
    const ushort* Bl = W1l + (size_t)e * 262144 + (size_t)(c0 + coln0) * 256;
    int w = tid >> 6, l = tid & 63;
    f32x4 acc[4] = {};
    int r = tid >> 2, c8 = (tid & 3) * 8;
    size_t arow = (size_t)tok[r] * 256;
    size_t brow = (size_t)r * 256;
    for (int k0 = 0; k0 < 256; k0 += 32) {
        *(uint4*)&LA[0][r][c8] = *(const uint4*)&Ah[arow + k0 + c8];
        *(uint4*)&LA[1][r][c8] = *(const uint4*)&Al[arow + k0 + c8];
        *(uint4*)&LB[0][r][c8] = *(const uint4*)&Bh[brow + k0 + c8];
        *(uint4*)&LB[1][r][c8] = *(const uint4*)&Bl[brow + k0 + c8];
        __syncthreads();
        int ar = (w << 4) + (l & 15), kg = (l >> 4) << 3;
        short8 ah = *(const short8*)&LA[0][ar][kg];
        short8 al = *(const short8*)&LA[1][ar][kg];
        #pragma unroll
        for (int f = 0; f < 4; ++f) {
            int br = (f << 4) + (l & 15);
            short8 bh = *(const short8*)&LB[0][br][kg];
            short8 bl = *(const short8*)&LB[1][br][kg];
            acc[f] = __builtin_amdgcn_mfma_f32_16x16x32_bf16(ah, bh, acc[f], 0, 0, 0);
            acc[f] = __builtin_amdgcn_mfma_f32_16x16x32_bf16(ah, bl, acc[f], 0, 0, 0);
            acc[f] = __builtin_amdgcn_mfma_f32_16x16x32_bf16(al, bh, acc[f], 0, 0, 0);
        }
        __syncthreads();
    }
    int orow = row0 + (w << 4) + ((l >> 4) << 2);
    int oc = coln0 + (l & 15);
    #pragma unroll
    for (int f = 0; f < 4; ++f) {
        int cl = oc + f * 16;
        float bv = b1l[(size_t)e * FFD + c0 + cl];
        #pragma unroll
        for (int rr = 0; rr < 4; ++rr) {
            int sr = orow + rr;
            if (sr < rowend) {
                float v = gelu_exact(acc[f][rr] + bv);
                ushort h, lo;
                split2(v, h, lo);
                hh[(size_t)sr * 256 + cl] = h;
                hl[(size_t)sr * 256 + cl] = lo;
            }
        }
    }
}

// ---------------- MFMA FFN2 (accumulate over chunks into f32 sout) ----------------
__global__ __launch_bounds__(256) void mfma_ffn2(const ushort* __restrict__ Ah,
                                                 const ushort* __restrict__ Al,
                                                 const ushort* __restrict__ W2h,
                                                 const ushort* __restrict__ W2l,
                                                 const float* __restrict__ b2l,
                                                 float* __restrict__ sout,
                                                 const int* __restrict__ ib, int c0) {
    int tileIdx = blockIdx.x;
    if (tileIdx >= ib[IB_NTILES]) return;
    int e = ib[IB_TILE_E + tileIdx];
    int row0 = ib[IB_TILE_R0 + tileIdx];
    int rowend = ib[IB_TILE_RE + tileIdx];
    __shared__ ushort LA[2][64][40];
    __shared__ ushort LB[2][64][40];
    int tid = threadIdx.x;
    int coln0 = blockIdx.y * 64;
    const ushort* Bh = W2h + (size_t)e * 262144 + c0;
    const ushort* Bl = W2l + (size_t)e * 262144 + c0;
    int w = tid >> 6, l = tid & 63;
    f32x4 acc[4] = {};
    int r = tid >> 2, c8 = (tid & 3) * 8;
    size_t arow = (size_t)(row0 + r) * 256;
    size_t brow = (size_t)(coln0 + r) * 1024;
    for (int k0 = 0; k0 < 256; k0 += 32) {
        *(uint4*)&LA[0][r][c8] = *(const uint4*)&Ah[arow + k0 + c8];
        *(uint4*)&LA[1][r][c8] = *(const uint4*)&Al[arow + k0 + c8];
        *(uint4*)&LB[0][r][c8] = *(const uint4*)&Bh[brow + k0 + c8];
        *(uint4*)&LB[1][r][c8] = *(const uint4*)&Bl[brow + k0 + c8];
        __syncthreads();
        int ar = (w << 4) + (l & 15), kg = (l >> 4) << 3;
        short8 ah = *(const short8*)&LA[0][ar][kg];
        short8 al = *(const short8*)&LA[1][ar][kg];
        #pragma unroll
        for (int f = 0; f < 4; ++f) {
            int br = (f << 4) + (l & 15);
            short8 bh = *(const short8*)&LB[0][br][kg];
            short8 bl = *(const short8*)&LB[1][br][kg];
            acc[f] = __builtin_amdgcn_mfma_f32_16x16x32_bf16(ah, bh, acc[f], 0, 0, 0);
            acc[f] = __builtin_amdgcn_mfma_f32_16x16x32_bf16(ah, bl, acc[f], 0, 0, 0);
            acc[f] = __builtin_amdgcn_mfma_f32_16x16x32_bf16(al, bh, acc[f], 0, 0, 0);
        }
        __syncthreads();
    }
    int orow = row0 + (w << 4) + ((l >> 4) << 2);
    int oc = coln0 + (l & 15);
    #pragma unroll
    for (int f = 0; f < 4; ++f) {
        int n = oc + f * 16;
        float bv = b2l[(size_t)e * DIM + n];
        #pragma unroll
        for (int rr = 0; rr < 4; ++rr) {
            int sr = orow + rr;
            if (sr < rowend) {
                size_t idx = (size_t)sr * 256 + n;
                if (c0 == 0) sout[idx] = acc[f][rr] + bv;
                else         sout[idx] += acc[f][rr];
            }
        }
    }
}

// ---------------- attention: KV-split (flash-decode), thread per q-row ----------------
__global__ __launch_bounds__(256) void attention_split(const float* __restrict__ qkv,
                                                       float* __restrict__ po,
                                                       float* __restrict__ pm,
                                                       float* __restrict__ pl) {
    int b = blockIdx.z, hh = blockIdx.y;
    int qt = blockIdx.x >> 2, split = blockIdx.x & 3;
    int sq = qt * 256 + threadIdx.x;
    const float* base = qkv + (size_t)b * 1024 * 768;
    const float scale = 0.17677669529663687f;
    float q[32];
    const float* qptr = base + (size_t)sq * 768 + hh * 32;
    #pragma unroll
    for (int i = 0; i < 8; ++i) {
        float4 v = *(const float4*)(qptr + i * 4);
        q[4 * i + 0] = v.x * scale;
        q[4 * i + 1] = v.y * scale;
        q[4 * i + 2] = v.z * scale;
        q[4 * i + 3] = v.w * scale;
    }
    float m = -1e30f, lsum = 0.0f;
    float o[32];
    #pragma unroll
    for (int i = 0; i < 32; ++i) o[i] = 0.0f;
    __shared__ float Kt[64][32];
    __shared__ float Vt[64][32];
    for (int kt = split * 4; kt < split * 4 + 4; ++kt) {
        __syncthreads();
        #pragma unroll
        for (int l = 0; l < 2; ++l) {
            int f4 = threadIdx.x + l * 256;
            int r = f4 >> 3, c = (f4 & 7) << 2;
            const float* kp = base + (size_t)(kt * 64 + r) * 768 + 256 + hh * 32 + c;
            *(float4*)&Kt[r][c] = *(const float4*)kp;
            const float* vp = base + (size_t)(kt * 64 + r) * 768 + 512 + hh * 32 + c;
            *(float4*)&Vt[r][c] = *(const float4*)vp;
        }
        __syncthreads();
        for (int jb = 0; jb < 4; ++jb) {
            float s[16];
            #pragma unroll
            for (int jj = 0; jj < 16; ++jj) {
                int j = jb * 16 + jj;
                float p0 = 0.f, p1 = 0.f, p2 = 0.f, p3 = 0.f;
                #pragma unroll
                for (int d4 = 0; d4 < 8; ++d4) {
                    float4 kk = *(const float4*)&Kt[j][d4 * 4];
                    p0 += q[4 * d4 + 0] * kk.x;
                    p1 += q[4 * d4 + 1] * kk.y;
                    p2 += q[4 * d4 + 2] * kk.z;
                    p3 += q[4 * d4 + 3] * kk.w;
                }
                s[jj] = (p0 + p1) + (p2 + p3);
            }
            float t8[8];
            #pragma unroll
            for (int i = 0; i < 8; ++i) t8[i] = fmaxf(s[i], s[i + 8]);
            #pragma unroll
            for (int i = 0; i < 4; ++i) t8[i] = fmaxf(t8[i], t8[i + 4]);
            float mt = fmaxf(fmaxf(t8[0], t8[1]), fmaxf(t8[2], t8[3]));
            float newm = fmaxf(m, mt);
            float corr = __expf(m - newm);
            m = newm;
            lsum *= corr;
            #pragma unroll
            for (int d = 0; d < 32; ++d) o[d] *= corr;
            #pragma unroll
            for (int jj = 0; jj < 16; ++jj) s[jj] = __expf(s[jj] - m);
            #pragma unroll
            for (int i = 0; i < 8; ++i) t8[i] = s[i] + s[i + 8];
            #pragma unroll
            for (int i = 0; i < 4; ++i) t8[i] = t8[i] + t8[i + 4];
            lsum += (t8[0] + t8[1]) + (t8[2] + t8[3]);
            #pragma unroll
            for (int jj = 0; jj < 16; ++jj) {
                int j = jb * 16 + jj;
                float p = s[jj];
                #pragma unroll
                for (int d4 = 0; d4 < 8; ++d4) {
                    float4 vv = *(const float4*)&Vt[j][d4 * 4];
                    o[4 * d4 + 0] += p * vv.x;
                    o[4 * d4 + 1] += p * vv.y;
                    o[4 * d4 + 2] += p * vv.z;
                    o[4 * d4 + 3] += p * vv.w;
                }
            }
        }
    }
    size_t row = ((size_t)(b * NH + hh) * NSPLIT + split) * 1024 + sq;
    pm[row] = m;
    pl[row] = lsum;
    float* op = po + row * 32;
    #pragma unroll
    for (int i = 0; i < 8; ++i) {
        float4 v;
        v.x = o[4 * i]; v.y = o[4 * i + 1]; v.z = o[4 * i + 2]; v.w = o[4 * i + 3];
        *(float4*)(op + i * 4) = v;
    }
}

// ---------------- attention combine -> bf16 split output (proj GEMM input) ----------------
__global__ __launch_bounds__(256) void attention_combine(const float* __restrict__ po,
                                                         const float* __restrict__ pm,
                                                         const float* __restrict__ pl,
                                                         ushort* __restrict__ ohi,
                                                         ushort* __restrict__ olo) {
    int gid = blockIdx.x * 256 + threadIdx.x;
    int d4 = gid & 7;
    int r = gid >> 3;
    int bh = r >> 10, sq = r & 1023;
    size_t rowbase = (size_t)bh * NSPLIT * 1024 + sq;
    float m0 = pm[rowbase], m1 = pm[rowbase + 1024], m2 = pm[rowbase + 2048], m3 = pm[rowbase + 3072];
    float m = fmaxf(fmaxf(m0, m1), fmaxf(m2, m3));
    float w0 = __expf(m0 - m), w1 = __expf(m1 - m), w2 = __expf(m2 - m), w3 = __expf(m3 - m);
    float l = w0 * pl[rowbase] + w1 * pl[rowbase + 1024] + w2 * pl[rowbase + 2048] + w3 * pl[rowbase + 3072];
    float4 a0 = *(const float4*)&po[(rowbase) * 32 + d4 * 4];
    float4 a1 = *(const float4*)&po[(rowbase + 1024) * 32 + d4 * 4];
    float4 a2 = *(const float4*)&po[(rowbase + 2048) * 32 + d4 * 4];
    float4 a3 = *(const float4*)&po[(rowbase + 3072) * 32 + d4 * 4];
    float inv = 1.0f / l;
    float o0 = (w0 * a0.x + w1 * a1.x + w2 * a2.x + w3 * a3.x) * inv;
    float o1 = (w0 * a0.y + w1 * a1.y + w2 * a2.y + w3 * a3.y) * inv;
    float o2 = (w0 * a0.z + w1 * a1.z + w2 * a2.z + w3 * a3.z) * inv;
    float o3 = (w0 * a0.w + w1 * a1.w + w2 * a2.w + w3 * a3.w) * inv;
    int h = bh & 7, b = bh >> 3;
    size_t idx = (size_t)(b * 1024 + sq) * 256 + h * 32 + d4 * 4;
    ushort h0, h1, h2, h3, l0, l1, l2, l3;
    split2(o0, h0, l0); split2(o1, h1, l1); split2(o2, h2, l2); split2(o3, h3, l3);
    uint2 ph, pll;
    ph.x = (uint)h0 | ((uint)h1 << 16); ph.y = (uint)h2 | ((uint)h3 << 16);
    pll.x = (uint)l0 | ((uint)l1 << 16); pll.y = (uint)l2 | ((uint)l3 << 16);
    *(uint2*)&ohi[idx] = ph;
    *(uint2*)&olo[idx] = pll;
}

// ---------------- gate + top2 ----------------
__global__ __launch_bounds__(256) void gate_topk(const float* __restrict__ lnb,
                                                 const float* __restrict__ gw,
                                                 const float* __restrict__ gb,
                                                 float* __restrict__ gv, int* __restrict__ ib) {
    int t = blockIdx.x * blockDim.x + threadIdx.x;
    const float* x = lnb + (size_t)t * DIM;
    float g[8];
    #pragma unroll
    for (int e = 0; e < 8; ++e) g[e] = gb[e];
    for (int d4 = 0; d4 < 64; ++d4) {
        float4 xv = *(const float4*)&x[d4 * 4];
        const float* w0 = gw + (size_t)(d4 * 4) * 8;
        #pragma unroll
        for (int e = 0; e < 8; ++e) g[e] += xv.x * w0[e];
        #pragma unroll
        for (int e = 0; e < 8; ++e) g[e] += xv.y * w0[8 + e];
        #pragma unroll
        for (int e = 0; e < 8; ++e) g[e] += xv.z * w0[16 + e];
        #pragma unroll
        for (int e = 0; e < 8; ++e) g[e] += xv.w * w0[24 + e];
    }
    int i0 = 0; float s0 = g[0];
    #pragma unroll
    for (int e = 1; e < 8; ++e) if (g[e] > s0) { s0 = g[e]; i0 = e; }
    int i1 = -1; float s1 = -1e30f;
    #pragma unroll
    for (int e = 0; e < 8; ++e) if (e != i0 && g[e] > s1) { s1 = g[e]; i1 = e; }
    float e1 = __expf(s1 - s0);
    float w0v = 1.0f / (1.0f + e1);
    float w1v = e1 / (1.0f + e1);
    gv[2 * t] = w0v; gv[2 * t + 1] = w1v;
    ib[IB_GIDX + 2 * t] = i0; ib[IB_GIDX + 2 * t + 1] = i1;
    atomicAdd(&ib[IB_COUNTS + i0], 1);
    atomicAdd(&ib[IB_COUNTS + i1], 1);
}

// ---------------- scan + tile table ----------------
__global__ void scan_tiles(int* ib) {
    if (threadIdx.x != 0 || blockIdx.x != 0) return;
    int off = 0, idx = 0;
    for (int e = 0; e < 8; ++e) {
        ib[IB_OFFS + e] = off;
        ib[IB_CURS + e] = off;
        int n = ib[IB_COUNTS + e];
        int nt = (n + 63) >> 6;
        for (int i = 0; i < nt; ++i) {
            ib[IB_TILE_E + idx] = e;
            ib[IB_TILE_R0 + idx] = off + i * 64;
            int re = off + ((i + 1) * 64 < n ? (i + 1) * 64 : n);
            ib[IB_TILE_RE + idx] = re;
            ++idx;
        }
        off += n;
    }
    ib[IB_NTILES] = idx;
}

// ---------------- scatter to slots ----------------
__global__ __launch_bounds__(256) void scatter_slots(int* ib) {
    int t = blockIdx.x * blockDim.x + threadIdx.x;
    #pragma unroll
    for (int k = 0; k < 2; ++k) {
        int e = ib[IB_GIDX + 2 * t + k];
        int pos = atomicAdd(&ib[IB_CURS + e], 1);
        ib[IB_STOK + pos] = t;
        ib[IB_SPOS + 2 * t + k] = pos;
    }
}

// ---------------- gather ----------------
__global__ __launch_bounds__(64) void moe_gather(float* __restrict__ xb,
                                                 const float* __restrict__ sout,
                                                 const float* __restrict__ gv,
                                                 const int* __restrict__ ib) {
    int t = blockIdx.x;
    int d = threadIdx.x * 4;
    int p0 = ib[IB_SPOS + 2 * t], p1 = ib[IB_SPOS + 2 * t + 1];
    float g0 = gv[2 * t], g1 = gv[2 * t + 1];
    float4 xv = *(float4*)&xb[(size_t)t * 256 + d];
    float4 s0 = *(const float4*)&sout[(size_t)p0 * 256 + d];
    float4 s1 = *(const float4*)&sout[(size_t)p1 * 256 + d];
    xv.x += g0 * s0.x + g1 * s1.x;
    xv.y += g0 * s0.y + g1 * s1.y;
    xv.z += g0 * s0.z + g1 * s1.z;
    xv.w += g0 * s0.w + g1 * s1.w;
    *(float4*)&xb[(size_t)t * 256 + d] = xv;
}

// ---------------- pooling ----------------
__global__ __launch_bounds__(256) void pool1(const float* __restrict__ xb, float* __restrict__ pp) {
    int b = blockIdx.x, ch = blockIdx.y, d = threadIdx.x;
    float s = 0.0f;
    for (int i = 0; i < 32; ++i) s += xb[((size_t)b * 1024 + ch * 32 + i) * 256 + d];
    pp[(size_t)(b * 32 + ch) * 256 + d] = s;
}
__global__ __launch_bounds__(256) void pool2(const float* __restrict__ pp, float* __restrict__ pool) {
    int b = blockIdx.x, d = threadIdx.x;
    float s = 0.0f;
    for (int c = 0; c < 32; ++c) s += pp[(size_t)(b * 32 + c) * 256 + d];
    pool[(size_t)b * 256 + d] = s * (1.0f / 1024.0f);
}

// ---------------- head ----------------
__global__ __launch_bounds__(256) void head_kernel(const float* __restrict__ pool,
                                                   const float* __restrict__ hw,
                                                   const float* __restrict__ hb,
                                                   float* __restrict__ out) {
    __shared__ float P[2048];
    int tid = threadIdx.x;
    for (int i = tid; i < 2048; i += 256) P[i] = pool[i];
    __syncthreads();
    int j = blockIdx.x * 256 + tid;
    if (j >= NOUT) return;
    float acc[8] = {};
    for (int d = 0; d < 256; ++d) {
        float w = hw[(size_t)d * NOUT + j];
        #pragma unroll
        for (int b = 0; b < 8; ++b) acc[b] += P[b * 256 + d] * w;
    }
    #pragma unroll
    for (int b = 0; b < 8; ++b) out[(size_t)b * NOUT + j] = acc[b] + hb[j];
}

extern "C" void kernel_launch(void* const* d_in, const int* in_sizes, int n_in,
                              void* d_out, int out_size, void* d_ws, size_t ws_size,
                              hipStream_t stream) {
    const float* x      = (const float*)d_in[0];
    const float* qkv_w  = (const float*)d_in[1];
    const float* qkv_b  = (const float*)d_in[2];
    const float* attn_w = (const float*)d_in[3];
    const float* attn_b = (const float*)d_in[4];
    const float* gate_w = (const float*)d_in[5];
    const float* gate_b = (const float*)d_in[6];
    const float* e_w1   = (const float*)d_in[7];
    const float* e_b1   = (const float*)d_in[8];
    const float* e_w2   = (const float*)d_in[9];
    const float* e_b2   = (const float*)d_in[10];
    const float* ln1_g  = (const float*)d_in[11];
    const float* ln1_b  = (const float*)d_in[12];
    const float* ln2_g  = (const float*)d_in[13];
    const float* ln2_b  = (const float*)d_in[14];
    const float* head_w = (const float*)d_in[15];
    const float* head_b = (const float*)d_in[16];
    float* out = (float*)d_out;
    float* wsf = (float*)d_ws;

    float* xb   = wsf + WS_X;
    float* lnb  = wsf + WS_LN;
    float* qkvb = wsf + WS_QKV;
    float* sob  = wsf + WS_SOUT;
    float* gv   = wsf + WS_GV;
    float* pp   = wsf + WS_PP;
    float* pool = wsf + WS_POOL;
    int*   ib   = (int*)(wsf + WS_INT);
    float* po   = wsf + WS_H;    // attention partial O (8.39M floats, spans WS_H+WS_SOUT)
    float* pm   = wsf + WS_PM;
    float* pl   = wsf + WS_PL;

    ushort* u16  = (ushort*)(wsf + WS_U16);
    ushort* lnh  = u16;                  // 2,097,152
    ushort* lnl  = u16 + 2097152;
    ushort* qwh  = u16 + 4194304;        // 196,608
    ushort* qwl  = u16 + 4390912;
    ushort* awh  = u16 + 4587520;        // 65,536
    ushort* awl  = u16 + 4653056;        // end 4,718,592 ushorts

    ushort* wT   = (ushort*)(wsf + WS_QKV);  // aliases qkvb (dead in MoE phase)
    ushort* w1th = wT;
    ushort* w1tl = wT + 2097152;
    ushort* w2th = wT + 4194304;
    ushort* w2tl = wT + 6291456;

    ushort* hh = (ushort*)(wsf + WS_H);      // h split (aliases po, dead then)
    ushort* hl = hh + 4194304;

    hipMemcpyAsync(xb, x, (size_t)TOK * DIM * sizeof(float), hipMemcpyDeviceToDevice, stream);

    for (int l = 0; l < NL; ++l) {
        // --- attention block ---
        ln_split<false><<<TOK / 4, 256, 0, stream>>>(xb, nullptr, lnh, lnl, ln1_g, ln1_b);
        split_transpose<<<dim3(8, 24, 1), 256, 0, stream>>>(
            qkv_w + (size_t)l * DIM * 3 * DIM, qwh, qwl, 256, 768);
        mfma_dense<false><<<dim3(128, 12), 256, 0, stream>>>(
            lnh, lnl, qwh, qwl, qkv_b + (size_t)l * 3 * DIM, qkvb, 768);
        attention_split<<<dim3(4 * NSPLIT, NH, 8), 256, 0, stream>>>(qkvb, po, pm, pl);
        attention_combine<<<2048, 256, 0, stream>>>(po, pm, pl, lnh, lnl);
        split_transpose<<<dim3(8, 8, 1), 256, 0, stream>>>(
            attn_w + (size_t)l * DIM * DIM, awh, awl, 256, 256);
        mfma_dense<true><<<dim3(128, 4), 256, 0, stream>>>(
            lnh, lnl, awh, awl, attn_b + (size_t)l * DIM, xb, 256);

        // --- MoE block ---
        ln_split<true><<<TOK / 4, 256, 0, stream>>>(xb, lnb, lnh, lnl, ln2_g, ln2_b);
        split_transpose<<<dim3(8, 32, 8), 256, 0, stream>>>(
            e_w1 + (size_t)l * NE * DIM * FFD, w1th, w1tl, 256, 1024);
        split_transpose<<<dim3(32, 8, 8), 256, 0, stream>>>(
            e_w2 + (size_t)l * NE * FFD * DIM, w2th, w2tl, 1024, 256);
        hipMemsetAsync(ib, 0, 64, stream);
        gate_topk<<<TOK / 256, 256, 0, stream>>>(
            lnb, gate_w + (size_t)l * DIM * NE, gate_b + (size_t)l * NE, gv, ib);
        scan_tiles<<<1, 64, 0, stream>>>(ib);
        scatter_slots<<<TOK / 256, 256, 0, stream>>>(ib);
        for (int c = 0; c < 4; ++c) {
            mfma_ffn1<<<dim3(272, 4), 256, 0, stream>>>(
                lnh, lnl, w1th, w1tl, e_b1 + (size_t)l * NE * FFD, hh, hl, ib, c * 256);
            mfma_ffn2<<<dim3(272, 4), 256, 0, stream>>>(
                hh, hl, w2th, w2tl, e_b2 + (size_t)l * NE * DIM, sob, ib, c * 256);
        }
        moe_gather<<<TOK, 64, 0, stream>>>(xb, sob, gv, ib);
    }

    pool1<<<dim3(8, 32), 256, 0, stream>>>(xb, pp);
    pool2<<<8, 256, 0, stream>>>(pp, pool);
    head_kernel<<<4, 256, 0, stream>>>(pool, head_w, head_b, out);
}

// Round 5
// 949.420 us; speedup vs baseline: 2.0711x; 1.3228x over previous
//
#include <hip/hip_runtime.h>
#include <math.h>

#define TOK   8192
#define DIM   256
#define NH    8
#define HDIM  32
#define FFD   1024
#define NE    8
#define NL    2
#define NOUT  1000
#define NSLOT 16384   // TOK*2

typedef unsigned int uint;
typedef unsigned short ushort;
typedef __attribute__((ext_vector_type(8))) short short8;
typedef __attribute__((ext_vector_type(4))) float f32x4;

// ---------------- workspace layout (float units) ----------------
#define WS_X     ((size_t)0)
#define WS_LN    (WS_X    + (size_t)TOK*DIM)       // f32 ln output (MoE gate input)
#define WS_QKV   (WS_LN   + (size_t)TOK*DIM)       // qkv split bf16 (2x 6291456 ushort); MoE: w1T/w2T splits
#define WS_H     (WS_QKV  + (size_t)TOK*3*DIM)     // attn: vT split; MoE: h split
#define WS_SOUT  (WS_H    + (size_t)NSLOT*256)     // MoE slot-out f32
#define WS_GV    (WS_SOUT + (size_t)NSLOT*256)
#define WS_PP    (WS_GV   + (size_t)TOK*2)
#define WS_POOL  (WS_PP   + (size_t)8*32*256)
#define WS_INT   (WS_POOL + (size_t)8*256)
#define WS_U16   (WS_INT  + (size_t)50048)         // ushort area: ln splits + small weight splits

// int region layout (int32 indices)
#define IB_COUNTS   0
#define IB_NTILES   8
#define IB_OFFS     16
#define IB_CURS     24
#define IB_TILE_E   32
#define IB_TILE_R0  320
#define IB_TILE_RE  608
#define IB_GIDX     896
#define IB_SPOS     17280
#define IB_STOK     33664

__device__ __forceinline__ float gelu_exact(float v) {
    return 0.5f * v * (1.0f + erff(v * 0.70710678118654752f));
}

__device__ __forceinline__ void split2(float x, ushort& h, ushort& lo) {
    uint u = __float_as_uint(x);
    uint hh = (u + 0x7FFFu + ((u >> 16) & 1u)) >> 16;
    h = (ushort)hh;
    float hf = __uint_as_float(hh << 16);
    float l = x - hf;
    uint ul = __float_as_uint(l);
    lo = (ushort)((ul + 0x7FFFu + ((ul >> 16) & 1u)) >> 16);
}

// ---------------- LayerNorm + bf16 split output ----------------
template<bool WF32>
__global__ __launch_bounds__(256) void ln_split(const float* __restrict__ x,
                                                float* __restrict__ out,
                                                ushort* __restrict__ ohi,
                                                ushort* __restrict__ olo,
                                                const float* __restrict__ g,
                                                const float* __restrict__ b) {
    int wave = threadIdx.x >> 6;
    int lane = threadIdx.x & 63;
    int t = blockIdx.x * 4 + wave;
    const float* xp = x + (size_t)t * DIM;
    float4 v = *(const float4*)&xp[lane * 4];
    float s = v.x + v.y + v.z + v.w;
    #pragma unroll
    for (int off = 32; off; off >>= 1) s += __shfl_xor(s, off);
    float mean = s * (1.0f / 256.0f);
    float dx = v.x - mean, dy = v.y - mean, dz = v.z - mean, dw = v.w - mean;
    float vs = dx * dx + dy * dy + dz * dz + dw * dw;
    #pragma unroll
    for (int off = 32; off; off >>= 1) vs += __shfl_xor(vs, off);
    float inv = rsqrtf(vs * (1.0f / 256.0f) + 1e-5f);
    float4 gg = *(const float4*)&g[lane * 4];
    float4 bb = *(const float4*)&b[lane * 4];
    float o0 = dx * inv * gg.x + bb.x;
    float o1 = dy * inv * gg.y + bb.y;
    float o2 = dz * inv * gg.z + bb.z;
    float o3 = dw * inv * gg.w + bb.w;
    size_t idx = (size_t)t * DIM + lane * 4;
    if (WF32) {
        float4 o; o.x = o0; o.y = o1; o.z = o2; o.w = o3;
        *(float4*)&out[idx] = o;
    }
    ushort h0, h1, h2, h3, l0, l1, l2, l3;
    split2(o0, h0, l0); split2(o1, h1, l1); split2(o2, h2, l2); split2(o3, h3, l3);
    uint2 ph, pl;
    ph.x = (uint)h0 | ((uint)h1 << 16); ph.y = (uint)h2 | ((uint)h3 << 16);
    pl.x = (uint)l0 | ((uint)l1 << 16); pl.y = (uint)l2 | ((uint)l3 << 16);
    *(uint2*)&ohi[idx] = ph;
    *(uint2*)&olo[idx] = pl;
}

// ---------------- split+transpose weights: src[K][N] (z matrices) -> T hi/lo [N][K] ----------------
__global__ __launch_bounds__(256) void split_transpose(const float* __restrict__ src,
                                                       ushort* __restrict__ dhi,
                                                       ushort* __restrict__ dlo,
                                                       int K, int N) {
    int z = blockIdx.z;
    const float* s = src + (size_t)z * K * N;
    ushort* th = dhi + (size_t)z * K * N;
    ushort* tl = dlo + (size_t)z * K * N;
    __shared__ float tile[32][33];
    int k0 = blockIdx.x * 32, n0 = blockIdx.y * 32;
    int tx = threadIdx.x & 31, ty = threadIdx.x >> 5;
    #pragma unroll
    for (int i = 0; i < 4; ++i) {
        int k = k0 + ty + i * 8;
        tile[ty + i * 8][tx] = s[(size_t)k * N + n0 + tx];
    }
    __syncthreads();
    #pragma unroll
    for (int i = 0; i < 4; ++i) {
        int n = n0 + ty + i * 8;
        float v = tile[tx][ty + i * 8];
        ushort h, lo;
        split2(v, h, lo);
        th[(size_t)n * K + k0 + tx] = h;
        tl[(size_t)n * K + k0 + tx] = lo;
    }
}

// ---------------- MFMA dense GEMM: MODE 0=f32, 1=f32+residual, 2=split bf16 out ----------------
template<int MODE>
__global__ __launch_bounds__(256) void mfma_dense(const ushort* __restrict__ Ah,
                                                  const ushort* __restrict__ Al,
                                                  const ushort* __restrict__ Bh,
                                                  const ushort* __restrict__ Bl,
                                                  const float* __restrict__ bias,
                                                  float* __restrict__ C,
                                                  ushort* __restrict__ Chi,
                                                  ushort* __restrict__ Clo, int N) {
    __shared__ ushort LA[2][64][40];
    __shared__ ushort LB[2][64][40];
    int tid = threadIdx.x;
    int row0 = blockIdx.x * 64, col0 = blockIdx.y * 64;
    int w = tid >> 6, l = tid & 63;
    f32x4 acc[4] = {};
    int r = tid >> 2, c8 = (tid & 3) * 8;
    size_t arow = (size_t)(row0 + r) * 256;
    size_t brow = (size_t)(col0 + r) * 256;
    for (int k0 = 0; k0 < 256; k0 += 32) {
        *(uint4*)&LA[0][r][c8] = *(const uint4*)&Ah[arow + k0 + c8];
        *(uint4*)&LA[1][r][c8] = *(const uint4*)&Al[arow + k0 + c8];
        *(uint4*)&LB[0][r][c8] = *(const uint4*)&Bh[brow + k0 + c8];
        *(uint4*)&LB[1][r][c8] = *(const uint4*)&Bl[brow + k0 + c8];
        __syncthreads();
        int ar = (w << 4) + (l & 15), kg = (l >> 4) << 3;
        short8 ah = *(const short8*)&LA[0][ar][kg];
        short8 al = *(const short8*)&LA[1][ar][kg];
        #pragma unroll
        for (int f = 0; f < 4; ++f) {
            int br = (f << 4) + (l & 15);
            short8 bh = *(const short8*)&LB[0][br][kg];
            short8 bl = *(const short8*)&LB[1][br][kg];
            acc[f] = __builtin_amdgcn_mfma_f32_16x16x32_bf16(ah, bh, acc[f], 0, 0, 0);
            acc[f] = __builtin_amdgcn_mfma_f32_16x16x32_bf16(ah, bl, acc[f], 0, 0, 0);
            acc[f] = __builtin_amdgcn_mfma_f32_16x16x32_bf16(al, bh, acc[f], 0, 0, 0);
        }
        __syncthreads();
    }
    int orow = row0 + (w << 4) + ((l >> 4) << 2);
    int oc = col0 + (l & 15);
    #pragma unroll
    for (int f = 0; f < 4; ++f) {
        int gc = oc + f * 16;
        float bv = bias[gc];
        #pragma unroll
        for (int rr = 0; rr < 4; ++rr) {
            size_t idx = (size_t)(orow + rr) * N + gc;
            float v = acc[f][rr] + bv;
            if (MODE == 1) v += C[idx];
            if (MODE == 2) {
                ushort h, lo;
                split2(v, h, lo);
                Chi[idx] = h;
                Clo[idx] = lo;
            } else {
                C[idx] = v;
            }
        }
    }
}

// ---------------- V transpose: qkv split V region -> vT[b,h][d 32][kv 1024] hi/lo ----------------
__global__ __launch_bounds__(256) void vt_kernel(const ushort* __restrict__ qkvh,
                                                 const ushort* __restrict__ qkvl,
                                                 ushort* __restrict__ vth,
                                                 ushort* __restrict__ vtl) {
    int bh = blockIdx.y;
    int b = bh >> 3, h = bh & 7;
    int kv0 = blockIdx.x * 32;
    __shared__ ushort smh[32][33], sml[32][33];
    int tid = threadIdx.x;
    #pragma unroll
    for (int p = 0; p < 4; ++p) {
        int kv = p * 8 + (tid >> 5);
        int d = tid & 31;
        size_t src = ((size_t)(b * 1024 + kv0 + kv)) * 768 + 512 + h * 32 + d;
        smh[kv][d] = qkvh[src];
        sml[kv][d] = qkvl[src];
    }
    __syncthreads();
    #pragma unroll
    for (int p = 0; p < 4; ++p) {
        int d = p * 8 + (tid >> 5);
        int kv = tid & 31;
        size_t dst = ((size_t)(bh * 32 + d)) * 1024 + kv0 + kv;
        vth[dst] = smh[kv][d];
        vtl[dst] = sml[kv][d];
    }
}

// ---------------- MFMA flash attention: block = (b, h, 64 q-rows), 4 waves x 16 q ----------------
__global__ __launch_bounds__(256, 4) void attention_mfma(const ushort* __restrict__ qkvh,
                                                         const ushort* __restrict__ qkvl,
                                                         const ushort* __restrict__ vth,
                                                         const ushort* __restrict__ vtl,
                                                         ushort* __restrict__ ohi,
                                                         ushort* __restrict__ olo) {
    int b = blockIdx.z, h = blockIdx.y;
    int q0 = blockIdx.x * 64;
    int tid = threadIdx.x;
    int w = tid >> 6, l = tid & 63;
    int c = l & 15, g = l >> 4;
    __shared__ ushort Kh[64][40], Kl[64][40];
    __shared__ ushort VTh[32][72], VTl[32][72];
    __shared__ ushort Ph[4][16][72], Pl[4][16][72];

    // Q A-fragment (per wave): row q0+w*16+c, k-dims g*8..g*8+7 (contiguous)
    size_t qbase = ((size_t)(b * 1024 + q0 + w * 16 + c)) * 768 + h * 32 + g * 8;
    short8 qa_h = *(const short8*)&qkvh[qbase];
    short8 qa_l = *(const short8*)&qkvl[qbase];

    f32x4 acc_o[2] = {};
    float mrow[4] = {-1e30f, -1e30f, -1e30f, -1e30f};
    float lrow[4] = {0.f, 0.f, 0.f, 0.f};
    const float scale = 0.17677669529663687f;

    int sr = tid >> 2, sc8 = (tid & 3) * 8;
    size_t kgbase = ((size_t)(b * 1024 + sr)) * 768 + 256 + h * 32 + sc8;
    int vd = tid >> 3, vk8 = (tid & 7) * 8;
    size_t vtbase = ((size_t)((b * 8 + h) * 32 + vd)) * 1024 + vk8;

    for (int kv0 = 0; kv0 < 1024; kv0 += 64) {
        __syncthreads();
        *(uint4*)&Kh[sr][sc8]   = *(const uint4*)&qkvh[kgbase + (size_t)kv0 * 768];
        *(uint4*)&Kl[sr][sc8]   = *(const uint4*)&qkvl[kgbase + (size_t)kv0 * 768];
        *(uint4*)&VTh[vd][vk8]  = *(const uint4*)&vth[vtbase + kv0];
        *(uint4*)&VTl[vd][vk8]  = *(const uint4*)&vtl[vtbase + kv0];
        __syncthreads();

        // --- QK^T: 4 16-col subtiles, 3-pass split ---
        f32x4 s4[4];
        #pragma unroll
        for (int t = 0; t < 4; ++t) {
            short8 kh = *(const short8*)&Kh[t * 16 + c][g * 8];
            short8 kl = *(const short8*)&Kl[t * 16 + c][g * 8];
            f32x4 a = {};
            a = __builtin_amdgcn_mfma_f32_16x16x32_bf16(qa_h, kh, a, 0, 0, 0);
            a = __builtin_amdgcn_mfma_f32_16x16x32_bf16(qa_l, kh, a, 0, 0, 0);
            a = __builtin_amdgcn_mfma_f32_16x16x32_bf16(qa_h, kl, a, 0, 0, 0);
            s4[t] = a;
        }
        #pragma unroll
        for (int t = 0; t < 4; ++t)
            #pragma unroll
            for (int rr = 0; rr < 4; ++rr) s4[t][rr] *= scale;

        // --- online softmax (row = q = g*4+rr across lanes c) ---
        #pragma unroll
        for (int rr = 0; rr < 4; ++rr) {
            float mt = fmaxf(fmaxf(s4[0][rr], s4[1][rr]), fmaxf(s4[2][rr], s4[3][rr]));
            mt = fmaxf(mt, __shfl_xor(mt, 1));
            mt = fmaxf(mt, __shfl_xor(mt, 2));
            mt = fmaxf(mt, __shfl_xor(mt, 4));
            mt = fmaxf(mt, __shfl_xor(mt, 8));
            float nm = fmaxf(mrow[rr], mt);
            float corr = __expf(mrow[rr] - nm);
            mrow[rr] = nm;
            float sum = 0.f;
            #pragma unroll
            for (int t = 0; t < 4; ++t) {
                float p = __expf(s4[t][rr] - nm);
                s4[t][rr] = p;
                sum += p;
            }
            sum += __shfl_xor(sum, 1);
            sum += __shfl_xor(sum, 2);
            sum += __shfl_xor(sum, 4);
            sum += __shfl_xor(sum, 8);
            lrow[rr] = lrow[rr] * corr + sum;
            acc_o[0][rr] *= corr;
            acc_o[1][rr] *= corr;
        }

        // --- write P (split) to per-wave LDS ---
        #pragma unroll
        for (int t = 0; t < 4; ++t)
            #pragma unroll
            for (int rr = 0; rr < 4; ++rr) {
                ushort ph_, pl_;
                split2(s4[t][rr], ph_, pl_);
                Ph[w][g * 4 + rr][t * 16 + c] = ph_;
                Pl[w][g * 4 + rr][t * 16 + c] = pl_;
            }
        asm volatile("s_waitcnt lgkmcnt(0)" ::: "memory");

        // --- PV: O[16q x 32d] += P[16q x 64kv] V[64kv x 32d], 3-pass split ---
        #pragma unroll
        for (int kt = 0; kt < 2; ++kt) {
            short8 pah = *(const short8*)&Ph[w][c][kt * 32 + g * 8];
            short8 pal = *(const short8*)&Pl[w][c][kt * 32 + g * 8];
            #pragma unroll
            for (int T = 0; T < 2; ++T) {
                short8 vh = *(const short8*)&VTh[T * 16 + c][kt * 32 + g * 8];
                short8 vl = *(const short8*)&VTl[T * 16 + c][kt * 32 + g * 8];
                acc_o[T] = __builtin_amdgcn_mfma_f32_16x16x32_bf16(pah, vh, acc_o[T], 0, 0, 0);
                acc_o[T] = __builtin_amdgcn_mfma_f32_16x16x32_bf16(pal, vh, acc_o[T], 0, 0, 0);
                acc_o[T] = __builtin_amdgcn_mfma_f32_16x16x32_bf16(pah, vl, acc_o[T], 0, 0, 0);
            }
        }
    }

    // --- epilogue: normalize, split, write ---
    #pragma unroll
    for (int rr = 0; rr < 4; ++rr) {
        float inv = 1.0f / lrow[rr];
        int q = q0 + w * 16 + g * 4 + rr;
        #pragma unroll
        for (int T = 0; T < 2; ++T) {
            float v = acc_o[T][rr] * inv;
            ushort hh_, ll_;
            split2(v, hh_, ll_);
            size_t idx = (size_t)(b * 1024 + q) * 256 + h * 32 + T * 16 + c;
            ohi[idx] = hh_;
            olo[idx] = ll_;
        }
    }
}

// ---------------- MFMA FFN1 (gathered rows, gelu, split output) ----------------
__global__ __launch_bounds__(256) void mfma_ffn1(const ushort* __restrict__ Ah,
                                                 const ushort* __restrict__ Al,
                                                 const ushort* __restrict__ W1h,
                                                 const ushort* __restrict__ W1l,
                                                 const float* __restrict__ b1l,
                                                 ushort* __restrict__ hh,
                                                 ushort* __restrict__ hl,
                                                 const int* __restrict__ ib, int c0) {
    int tileIdx = blockIdx.x;
    if (tileIdx >= ib[IB_NTILES]) return;
    int e = ib[IB_TILE_E + tileIdx];
    int row0 = ib[IB_TILE_R0 + tileIdx];
    int rowend = ib[IB_TILE_RE + tileIdx];
    __shared__ ushort LA[2][64][40];
    __shared__ ushort LB[2][64][40];
    __shared__ int tok[64];
    int tid = threadIdx.x;
    if (tid < 64) {
        int sr = row0 + tid;
        tok[tid] = ib[IB_STOK + (sr < rowend ? sr : row0)];
    }
    __syncthreads();
    int coln0 = blockIdx.y * 64;
    const ushort* Bh = W1h + (size_t)e * 262144 + (size_t)(c0 + coln0) * 256;
    const ushort* Bl = W1l + (size_t)e * 262144 + (size_t)(c0 + coln0) * 256;
    int w = tid >> 6, l = tid & 63;
    f32x4 acc[4] = {};
    int r = tid >> 2, c8 = (tid & 3) * 8;
    size_t arow = (size_t)tok[r] * 256;
    size_t brow = (size_t)r * 256;
    for (int k0 = 0; k0 < 256; k0 += 32) {
        *(uint4*)&LA[0][r][c8] = *(const uint4*)&Ah[arow + k0 + c8];
        *(uint4*)&LA[1][r][c8] = *(const uint4*)&Al[arow + k0 + c8];
        *(uint4*)&LB[0][r][c8] = *(const uint4*)&Bh[brow + k0 + c8];
        *(uint4*)&LB[1][r][c8] = *(const uint4*)&Bl[brow + k0 + c8];
        __syncthreads();
        int ar = (w << 4) + (l & 15), kg = (l >> 4) << 3;
        short8 ah = *(const short8*)&LA[0][ar][kg];
        short8 al = *(const short8*)&LA[1][ar][kg];
        #pragma unroll
        for (int f = 0; f < 4; ++f) {
            int br = (f << 4) + (l & 15);
            short8 bh = *(const short8*)&LB[0][br][kg];
            short8 bl = *(const short8*)&LB[1][br][kg];
            acc[f] = __builtin_amdgcn_mfma_f32_16x16x32_bf16(ah, bh, acc[f], 0, 0, 0);
            acc[f] = __builtin_amdgcn_mfma_f32_16x16x32_bf16(ah, bl, acc[f], 0, 0, 0);
            acc[f] = __builtin_amdgcn_mfma_f32_16x16x32_bf16(al, bh, acc[f], 0, 0, 0);
        }
        __syncthreads();
    }
    int orow = row0 + (w << 4) + ((l >> 4) << 2);
    int oc = coln0 + (l & 15);
    #pragma unroll
    for (int f = 0; f < 4; ++f) {
        int cl = oc + f * 16;
        float bv = b1l[(size_t)e * FFD + c0 + cl];
        #pragma unroll
        for (int rr = 0; rr < 4; ++rr) {
            int sr = orow + rr;
            if (sr < rowend) {
                float v = gelu_exact(acc[f][rr] + bv);
                ushort h, lo;
                split2(v, h, lo);
                hh[(size_t)sr * 256 + cl] = h;
                hl[(size_t)sr * 256 + cl] = lo;
            }
        }
    }
}

// ---------------- MFMA FFN2 (accumulate over chunks into f32 sout) ----------------
__global__ __launch_bounds__(256) void mfma_ffn2(const ushort* __restrict__ Ah,
                                                 const ushort* __restrict__ Al,
                                                 const ushort* __restrict__ W2h,
                                                 const ushort* __restrict__ W2l,
                                                 const float* __restrict__ b2l,
                                                 float* __restrict__ sout,
                                                 const int* __restrict__ ib, int c0) {
    int tileIdx = blockIdx.x;
    if (tileIdx >= ib[IB_NTILES]) return;
    int e = ib[IB_TILE_E + tileIdx];
    int row0 = ib[IB_TILE_R0 + tileIdx];
    int rowend = ib[IB_TILE_RE + tileIdx];
    __shared__ ushort LA[2][64][40];
    __shared__ ushort LB[2][64][40];
    int tid = threadIdx.x;
    int coln0 = blockIdx.y * 64;
    const ushort* Bh = W2h + (size_t)e * 262144 + c0;
    const ushort* Bl = W2l + (size_t)e * 262144 + c0;
    int w = tid >> 6, l = tid & 63;
    f32x4 acc[4] = {};
    int r = tid >> 2, c8 = (tid & 3) * 8;
    size_t arow = (size_t)(row0 + r) * 256;
    size_t brow = (size_t)(coln0 + r) * 1024;
    for (int k0 = 0; k0 < 256; k0 += 32) {
        *(uint4*)&LA[0][r][c8] = *(const uint4*)&Ah[arow + k0 + c8];
        *(uint4*)&LA[1][r][c8] = *(const uint4*)&Al[arow + k0 + c8];
        *(uint4*)&LB[0][r][c8] = *(const uint4*)&Bh[brow + k0 + c8];
        *(uint4*)&LB[1][r][c8] = *(const uint4*)&Bl[brow + k0 + c8];
        __syncthreads();
        int ar = (w << 4) + (l & 15), kg = (l >> 4) << 3;
        short8 ah = *(const short8*)&LA[0][ar][kg];
        short8 al = *(const short8*)&LA[1][ar][kg];
        #pragma unroll
        for (int f = 0; f < 4; ++f) {
            int br = (f << 4) + (l & 15);
            short8 bh = *(const short8*)&LB[0][br][kg];
            short8 bl = *(const short8*)&LB[1][br][kg];
            acc[f] = __builtin_amdgcn_mfma_f32_16x16x32_bf16(ah, bh, acc[f], 0, 0, 0);
            acc[f] = __builtin_amdgcn_mfma_f32_16x16x32_bf16(ah, bl, acc[f], 0, 0, 0);
            acc[f] = __builtin_amdgcn_mfma_f32_16x16x32_bf16(al, bh, acc[f], 0, 0, 0);
        }
        __syncthreads();
    }
    int orow = row0 + (w << 4) + ((l >> 4) << 2);
    int oc = coln0 + (l & 15);
    #pragma unroll
    for (int f = 0; f < 4; ++f) {
        int n = oc + f * 16;
        float bv = b2l[(size_t)e * DIM + n];
        #pragma unroll
        for (int rr = 0; rr < 4; ++rr) {
            int sr = orow + rr;
            if (sr < rowend) {
                size_t idx = (size_t)sr * 256 + n;
                if (c0 == 0) sout[idx] = acc[f][rr] + bv;
                else         sout[idx] += acc[f][rr];
            }
        }
    }
}

// ---------------- gate + top2 ----------------
__global__ __launch_bounds__(256) void gate_topk(const float* __restrict__ lnb,
                                                 const float* __restrict__ gw,
                                                 const float* __restrict__ gb,
                                                 float* __restrict__ gv, int* __restrict__ ib) {
    int t = blockIdx.x * blockDim.x + threadIdx.x;
    const float* x = lnb + (size_t)t * DIM;
    float g[8];
    #pragma unroll
    for (int e = 0; e < 8; ++e) g[e] = gb[e];
    for (int d4 = 0; d4 < 64; ++d4) {
        float4 xv = *(const float4*)&x[d4 * 4];
        const float* w0 = gw + (size_t)(d4 * 4) * 8;
        #pragma unroll
        for (int e = 0; e < 8; ++e) g[e] += xv.x * w0[e];
        #pragma unroll
        for (int e = 0; e < 8; ++e) g[e] += xv.y * w0[8 + e];
        #pragma unroll
        for (int e = 0; e < 8; ++e) g[e] += xv.z * w0[16 + e];
        #pragma unroll
        for (int e = 0; e < 8; ++e) g[e] += xv.w * w0[24 + e];
    }
    int i0 = 0; float s0 = g[0];
    #pragma unroll
    for (int e = 1; e < 8; ++e) if (g[e] > s0) { s0 = g[e]; i0 = e; }
    int i1 = -1; float s1 = -1e30f;
    #pragma unroll
    for (int e = 0; e < 8; ++e) if (e != i0 && g[e] > s1) { s1 = g[e]; i1 = e; }
    float e1 = __expf(s1 - s0);
    float w0v = 1.0f / (1.0f + e1);
    float w1v = e1 / (1.0f + e1);
    gv[2 * t] = w0v; gv[2 * t + 1] = w1v;
    ib[IB_GIDX + 2 * t] = i0; ib[IB_GIDX + 2 * t + 1] = i1;
    atomicAdd(&ib[IB_COUNTS + i0], 1);
    atomicAdd(&ib[IB_COUNTS + i1], 1);
}

// ---------------- scan + tile table ----------------
__global__ void scan_tiles(int* ib) {
    if (threadIdx.x != 0 || blockIdx.x != 0) return;
    int off = 0, idx = 0;
    for (int e = 0; e < 8; ++e) {
        ib[IB_OFFS + e] = off;
        ib[IB_CURS + e] = off;
        int n = ib[IB_COUNTS + e];
        int nt = (n + 63) >> 6;
        for (int i = 0; i < nt; ++i) {
            ib[IB_TILE_E + idx] = e;
            ib[IB_TILE_R0 + idx] = off + i * 64;
            int re = off + ((i + 1) * 64 < n ? (i + 1) * 64 : n);
            ib[IB_TILE_RE + idx] = re;
            ++idx;
        }
        off += n;
    }
    ib[IB_NTILES] = idx;
}

// ---------------- scatter to slots ----------------
__global__ __launch_bounds__(256) void scatter_slots(int* ib) {
    int t = blockIdx.x * blockDim.x + threadIdx.x;
    #pragma unroll
    for (int k = 0; k < 2; ++k) {
        int e = ib[IB_GIDX + 2 * t + k];
        int pos = atomicAdd(&ib[IB_CURS + e], 1);
        ib[IB_STOK + pos] = t;
        ib[IB_SPOS + 2 * t + k] = pos;
    }
}

// ---------------- gather ----------------
__global__ __launch_bounds__(64) void moe_gather(float* __restrict__ xb,
                                                 const float* __restrict__ sout,
                                                 const float* __restrict__ gv,
                                                 const int* __restrict__ ib) {
    int t = blockIdx.x;
    int d = threadIdx.x * 4;
    int p0 = ib[IB_SPOS + 2 * t], p1 = ib[IB_SPOS + 2 * t + 1];
    float g0 = gv[2 * t], g1 = gv[2 * t + 1];
    float4 xv = *(float4*)&xb[(size_t)t * 256 + d];
    float4 s0 = *(const float4*)&sout[(size_t)p0 * 256 + d];
    float4 s1 = *(const float4*)&sout[(size_t)p1 * 256 + d];
    xv.x += g0 * s0.x + g1 * s1.x;
    xv.y += g0 * s0.y + g1 * s1.y;
    xv.z += g0 * s0.z + g1 * s1.z;
    xv.w += g0 * s0.w + g1 * s1.w;
    *(float4*)&xb[(size_t)t * 256 + d] = xv;
}

// ---------------- pooling ----------------
__global__ __launch_bounds__(256) void pool1(const float* __restrict__ xb, float* __restrict__ pp) {
    int b = blockIdx.x, ch = blockIdx.y, d = threadIdx.x;
    float s = 0.0f;
    for (int i = 0; i < 32; ++i) s += xb[((size_t)b * 1024 + ch * 32 + i) * 256 + d];
    pp[(size_t)(b * 32 + ch) * 256 + d] = s;
}
__global__ __launch_bounds__(256) void pool2(const float* __restrict__ pp, float* __restrict__ pool) {
    int b = blockIdx.x, d = threadIdx.x;
    float s = 0.0f;
    for (int c = 0; c < 32; ++c) s += pp[(size_t)(b * 32 + c) * 256 + d];
    pool[(size_t)b * 256 + d] = s * (1.0f / 1024.0f);
}

// ---------------- head ----------------
__global__ __launch_bounds__(256) void head_kernel(const float* __restrict__ pool,
                                                   const float* __restrict__ hw,
                                                   const float* __restrict__ hb,
                                                   float* __restrict__ out) {
    __shared__ float P[2048];
    int tid = threadIdx.x;
    for (int i = tid; i < 2048; i += 256) P[i] = pool[i];
    __syncthreads();
    int j = blockIdx.x * 256 + tid;
    if (j >= NOUT) return;
    float acc[8] = {};
    for (int d = 0; d < 256; ++d) {
        float w = hw[(size_t)d * NOUT + j];
        #pragma unroll
        for (int b = 0; b < 8; ++b) acc[b] += P[b * 256 + d] * w;
    }
    #pragma unroll
    for (int b = 0; b < 8; ++b) out[(size_t)b * NOUT + j] = acc[b] + hb[j];
}

extern "C" void kernel_launch(void* const* d_in, const int* in_sizes, int n_in,
                              void* d_out, int out_size, void* d_ws, size_t ws_size,
                              hipStream_t stream) {
    const float* x      = (const float*)d_in[0];
    const float* qkv_w  = (const float*)d_in[1];
    const float* qkv_b  = (const float*)d_in[2];
    const float* attn_w = (const float*)d_in[3];
    const float* attn_b = (const float*)d_in[4];
    const float* gate_w = (const float*)d_in[5];
    const float* gate_b = (const float*)d_in[6];
    const float* e_w1   = (const float*)d_in[7];
    const float* e_b1   = (const float*)d_in[8];
    const float* e_w2   = (const float*)d_in[9];
    const float* e_b2   = (const float*)d_in[10];
    const float* ln1_g  = (const float*)d_in[11];
    const float* ln1_b  = (const float*)d_in[12];
    const float* ln2_g  = (const float*)d_in[13];
    const float* ln2_b  = (const float*)d_in[14];
    const float* head_w = (const float*)d_in[15];
    const float* head_b = (const float*)d_in[16];
    float* out = (float*)d_out;
    float* wsf = (float*)d_ws;

    float* xb   = wsf + WS_X;
    float* lnb  = wsf + WS_LN;
    float* sob  = wsf + WS_SOUT;
    float* gv   = wsf + WS_GV;
    float* pp   = wsf + WS_PP;
    float* pool = wsf + WS_POOL;
    int*   ib   = (int*)(wsf + WS_INT);

    // qkv split bf16 (attention phase), aliased by w1T/w2T (MoE phase)
    ushort* qkvsh = (ushort*)(wsf + WS_QKV);
    ushort* qkvsl = qkvsh + 6291456;
    ushort* wT    = (ushort*)(wsf + WS_QKV);
    ushort* w1th  = wT;
    ushort* w1tl  = wT + 2097152;
    ushort* w2th  = wT + 4194304;
    ushort* w2tl  = wT + 6291456;

    // V-transpose split (attention phase) / h split (MoE phase) share WS_H
    ushort* vth = (ushort*)(wsf + WS_H);
    ushort* vtl = vth + 2097152;
    ushort* hh  = (ushort*)(wsf + WS_H);
    ushort* hl  = hh + 4194304;

    ushort* u16  = (ushort*)(wsf + WS_U16);
    ushort* lnh  = u16;
    ushort* lnl  = u16 + 2097152;
    ushort* qwh  = u16 + 4194304;
    ushort* qwl  = u16 + 4390912;
    ushort* awh  = u16 + 4587520;
    ushort* awl  = u16 + 4653056;

    hipMemcpyAsync(xb, x, (size_t)TOK * DIM * sizeof(float), hipMemcpyDeviceToDevice, stream);

    for (int l = 0; l < NL; ++l) {
        // --- attention block ---
        ln_split<false><<<TOK / 4, 256, 0, stream>>>(xb, nullptr, lnh, lnl, ln1_g, ln1_b);
        split_transpose<<<dim3(8, 24, 1), 256, 0, stream>>>(
            qkv_w + (size_t)l * DIM * 3 * DIM, qwh, qwl, 256, 768);
        mfma_dense<2><<<dim3(128, 12), 256, 0, stream>>>(
            lnh, lnl, qwh, qwl, qkv_b + (size_t)l * 3 * DIM, nullptr, qkvsh, qkvsl, 768);
        vt_kernel<<<dim3(32, 64), 256, 0, stream>>>(qkvsh, qkvsl, vth, vtl);
        attention_mfma<<<dim3(16, NH, 8), 256, 0, stream>>>(qkvsh, qkvsl, vth, vtl, lnh, lnl);
        split_transpose<<<dim3(8, 8, 1), 256, 0, stream>>>(
            attn_w + (size_t)l * DIM * DIM, awh, awl, 256, 256);
        mfma_dense<1><<<dim3(128, 4), 256, 0, stream>>>(
            lnh, lnl, awh, awl, attn_b + (size_t)l * DIM, xb, nullptr, nullptr, 256);

        // --- MoE block ---
        ln_split<true><<<TOK / 4, 256, 0, stream>>>(xb, lnb, lnh, lnl, ln2_g, ln2_b);
        split_transpose<<<dim3(8, 32, 8), 256, 0, stream>>>(
            e_w1 + (size_t)l * NE * DIM * FFD, w1th, w1tl, 256, 1024);
        split_transpose<<<dim3(32, 8, 8), 256, 0, stream>>>(
            e_w2 + (size_t)l * NE * FFD * DIM, w2th, w2tl, 1024, 256);
        hipMemsetAsync(ib, 0, 64, stream);
        gate_topk<<<TOK / 256, 256, 0, stream>>>(
            lnb, gate_w + (size_t)l * DIM * NE, gate_b + (size_t)l * NE, gv, ib);
        scan_tiles<<<1, 64, 0, stream>>>(ib);
        scatter_slots<<<TOK / 256, 256, 0, stream>>>(ib);
        for (int c = 0; c < 4; ++c) {
            mfma_ffn1<<<dim3(272, 4), 256, 0, stream>>>(
                lnh, lnl, w1th, w1tl, e_b1 + (size_t)l * NE * FFD, hh, hl, ib, c * 256);
            mfma_ffn2<<<dim3(272, 4), 256, 0, stream>>>(
                hh, hl, w2th, w2tl, e_b2 + (size_t)l * NE * DIM, sob, ib, c * 256);
        }
        moe_gather<<<TOK, 64, 0, stream>>>(xb, sob, gv, ib);
    }

    pool1<<<dim3(8, 32), 256, 0, stream>>>(xb, pp);
    pool2<<<8, 256, 0, stream>>>(pp, pool);
    head_kernel<<<4, 256, 0, stream>>>(pool, head_w, head_b, out);
}